// Round 17
// baseline (4351.300 us; speedup 1.0000x reference)
//
#include <hip/hip_runtime.h>
#include <cstddef>
#include <cstdint>

// ---------------- problem constants ----------------
constexpr int CV    = 12000;
constexpr int CVP2  = 12288;
constexpr int CWE   = 1000;
constexpr int CFEAT = 2048;
constexpr int CFE   = 1024;
constexpr int CH    = 1024;
constexpr int CAH   = 512;
constexpr int CNREG = 36;
constexpr int CB    = 128;
constexpr int CT    = 17;
constexpr int G4    = 4096;
constexpr int XH    = 2048;    // xh  = [h_lang | h_att]
constexpr int XL3   = 3072;    // xl3 = [att_res | h_att | h_lang_prev]
constexpr int NGB   = 1024;    // gate grid blocks (256 x 4)
constexpr int NTAIL = 128;     // tail blocks doing fused pointwise

#define CDIV(a,b) (((a)+(b)-1)/(b))

typedef __bf16 bf16_t;
typedef __bf16 bf16x8 __attribute__((ext_vector_type(8)));
typedef __bf16 bf16x4 __attribute__((ext_vector_type(4)));
typedef float  f32x4  __attribute__((ext_vector_type(4)));

typedef __attribute__((address_space(3))) uint32_t lds_u32;
typedef const __attribute__((address_space(1))) uint32_t glb_u32;

struct Seg { const bf16_t* A; const bf16_t* W; int lda, ldw, kt; };

// =======================================================================
// pre_gemm: C = A @ W^T + b. BM=128, BN=64, BK=64. (unchanged, proven)
// =======================================================================
template<bool RELU, bool OUTBF, int SWZ>
__global__ __launch_bounds__(256)
void pre_gemm(Seg s0, int inner, const float* __restrict__ bias1,
              void* __restrict__ Cout, int ldc)
{
    const int tid = threadIdx.x;
    const int wid = tid >> 6, lane = tid & 63;
    const int wr = wid >> 1, wc = wid & 1;
    const int llo = lane & 15, lhi = lane >> 4;
    const int nb = gridDim.x, id = blockIdx.x;
    const int sw = (id & 7) * (nb >> 3) + (id >> 3);
    int m0, n0;
    if (SWZ == 1)      { n0 = (sw / inner) * 64;  m0 = (sw % inner) * 128; }
    else if (SWZ == 2) { m0 = (sw / inner) * 128; n0 = (sw % inner) * 64;  }
    else {
        const int xcd = id & 7, idx = id >> 3;
        m0 = (((xcd >> 2) << 3) + (idx & 7)) * 128;
        n0 = (((xcd & 3) << 4) + (idx >> 3)) * 64;
    }

    __shared__ __align__(16) uint8_t sm[2][24576];

    const int TT = s0.kt;
    f32x4 acc[4][2] = {};
    uint4 ra[4], rb[2];
    const int srow = tid >> 3, sc = tid & 7;
    const int cswz = (sc ^ (srow & 7)) << 4;

    auto load_tile = [&](int ti) {
        const int k0 = ti << 6;
        #pragma unroll
        for (int i = 0; i < 4; ++i)
            ra[i] = *(const uint4*)(s0.A + (size_t)(m0 + i * 32 + srow) * s0.lda + k0 + sc * 8);
        #pragma unroll
        for (int i = 0; i < 2; ++i)
            rb[i] = *(const uint4*)(s0.W + (size_t)(n0 + i * 32 + srow) * s0.ldw + k0 + sc * 8);
    };
    auto write_tile = [&](int buf) {
        uint8_t* base = sm[buf];
        #pragma unroll
        for (int i = 0; i < 4; ++i) *(uint4*)(base + (i * 32 + srow) * 128 + cswz) = ra[i];
        #pragma unroll
        for (int i = 0; i < 2; ++i) *(uint4*)(base + 16384 + (i * 32 + srow) * 128 + cswz) = rb[i];
    };
    auto compute = [&](int buf) {
        const uint8_t* base = sm[buf];
        const int r7 = llo & 7;
        #pragma unroll
        for (int kk = 0; kk < 2; ++kk) {
            const int coff = ((kk * 4 + lhi) ^ r7) << 4;
            bf16x8 af[4], bg[2];
            #pragma unroll
            for (int fm = 0; fm < 4; ++fm)
                af[fm] = *(const bf16x8*)(base + (wr * 64 + fm * 16 + llo) * 128 + coff);
            #pragma unroll
            for (int fn = 0; fn < 2; ++fn)
                bg[fn] = *(const bf16x8*)(base + 16384 + (wc * 32 + fn * 16 + llo) * 128 + coff);
            #pragma unroll
            for (int fm = 0; fm < 4; ++fm)
                #pragma unroll
                for (int fn = 0; fn < 2; ++fn)
                    acc[fm][fn] = __builtin_amdgcn_mfma_f32_16x16x32_bf16(
                        af[fm], bg[fn], acc[fm][fn], 0, 0, 0);
        }
    };

    load_tile(0); write_tile(0);
    load_tile(1);
    __syncthreads();
    int cur = 0;
    for (int ti = 0; ti < TT; ++ti) {
        if (ti + 1 < TT) write_tile(cur ^ 1);
        if (ti + 2 < TT) load_tile(ti + 2);
        compute(cur);
        __syncthreads();
        cur ^= 1;
    }

    if (OUTBF) {
        bf16_t* st = (bf16_t*)sm[0];
        #pragma unroll
        for (int fn = 0; fn < 2; ++fn) {
            const int lcol = wc * 32 + fn * 16 + llo;
            const float b = bias1 ? bias1[n0 + lcol] : 0.f;
            #pragma unroll
            for (int fm = 0; fm < 4; ++fm)
                #pragma unroll
                for (int r = 0; r < 4; ++r) {
                    float v = acc[fm][fn][r] + b;
                    if (RELU) v = fmaxf(v, 0.f);
                    st[(wr * 64 + fm * 16 + lhi * 4 + r) * 64 + lcol] = (bf16_t)v;
                }
        }
        __syncthreads();
        #pragma unroll
        for (int i = 0; i < 4; ++i) {
            const int q = tid + i * 256;
            const int row = q >> 3, ch = q & 7;
            *(uint4*)((bf16_t*)Cout + (size_t)(m0 + row) * ldc + n0 + ch * 8)
                = *(const uint4*)&st[row * 64 + ch * 8];
        }
    } else {
        const int colb = n0 + wc * 32;
        const int rowb = m0 + wr * 64 + lhi * 4;
        #pragma unroll
        for (int fn = 0; fn < 2; ++fn) {
            const int col = colb + fn * 16 + llo;
            const float b = bias1 ? bias1[col] : 0.f;
            #pragma unroll
            for (int fm = 0; fm < 4; ++fm)
                #pragma unroll
                for (int r = 0; r < 4; ++r) {
                    float v = acc[fm][fn][r] + b;
                    if (RELU) v = fmaxf(v, 0.f);
                    ((float*)Cout)[(size_t)(rowb + fm * 16 + r) * ldc + col] = v;
                }
        }
    }
}

// =======================================================================
// cls_gemm (unchanged)
// =======================================================================
__global__ __launch_bounds__(256)
void cls_gemm(const bf16_t* __restrict__ A, const bf16_t* __restrict__ W,
              const float* __restrict__ bias, bf16_t* __restrict__ Cout)
{
    const int tid = threadIdx.x;
    const int wid = tid >> 6, lane = tid & 63;
    const int wr = wid >> 1, wc = wid & 1;
    const int llo = lane & 15, lhi = lane >> 4;
    const int id = blockIdx.x;
    const int xcd = id & 7, idx = id >> 3;
    const int mg = xcd & 1, ng = xcd >> 1;
    const int m0 = (mg * 8 + (idx & 7)) * 128;
    const int n0 = (ng * 24 + (idx >> 3)) * 128;

    __shared__ __align__(16) uint8_t pool[65536];
    auto bufA = [&](int b) { return pool + b * 16384; };
    auto bufB = [&](int b) { return pool + 32768 + b * 16384; };

    constexpr int TT = 16;
    f32x4 acc[4][4] = {};
    uint4 ra[4], rbv[4];

    auto load_tile = [&](int ti) {
        const int k0 = ti << 6;
        #pragma unroll
        for (int i = 0; i < 4; ++i) {
            const int q = tid + i * 256;
            const int row = q >> 3, c = q & 7;
            ra[i]  = *(const uint4*)(A + (size_t)(m0 + row) * CH + k0 + c * 8);
            rbv[i] = *(const uint4*)(W + (size_t)(n0 + row) * CH + k0 + c * 8);
        }
    };
    auto write_tile = [&](int buf) {
        #pragma unroll
        for (int i = 0; i < 4; ++i) {
            const int q = tid + i * 256;
            const int row = q >> 3, c = q & 7;
            const int o = row * 128 + ((c ^ (row & 7)) << 4);
            *(uint4*)(bufA(buf) + o) = ra[i];
            *(uint4*)(bufB(buf) + o) = rbv[i];
        }
    };
    auto compute = [&](int buf) {
        const int r7 = llo & 7;
        #pragma unroll
        for (int kk = 0; kk < 2; ++kk) {
            const int coff = ((kk * 4 + lhi) ^ r7) << 4;
            bf16x8 af[4], bg[4];
            #pragma unroll
            for (int fm = 0; fm < 4; ++fm)
                af[fm] = *(const bf16x8*)(bufA(buf) + (wr * 64 + fm * 16 + llo) * 128 + coff);
            #pragma unroll
            for (int fn = 0; fn < 4; ++fn)
                bg[fn] = *(const bf16x8*)(bufB(buf) + (wc * 64 + fn * 16 + llo) * 128 + coff);
            #pragma unroll
            for (int fm = 0; fm < 4; ++fm)
                #pragma unroll
                for (int fn = 0; fn < 4; ++fn)
                    acc[fm][fn] = __builtin_amdgcn_mfma_f32_16x16x32_bf16(
                        af[fm], bg[fn], acc[fm][fn], 0, 0, 0);
        }
    };

    load_tile(0); write_tile(0);
    load_tile(1);
    __syncthreads();
    int cur = 0;
    for (int ti = 0; ti < TT; ++ti) {
        if (ti + 1 < TT) write_tile(cur ^ 1);
        if (ti + 2 < TT) load_tile(ti + 2);
        compute(cur);
        __syncthreads();
        cur ^= 1;
    }

    constexpr int STR = 136;
    bf16_t* st = (bf16_t*)pool;
    #pragma unroll
    for (int fn = 0; fn < 4; ++fn) {
        const int lcol = wc * 64 + fn * 16 + llo;
        const int col = n0 + lcol;
        const float b = (col < CV) ? bias[col] : 0.f;
        #pragma unroll
        for (int fm = 0; fm < 4; ++fm)
            #pragma unroll
            for (int r = 0; r < 4; ++r)
                st[(wr * 64 + fm * 16 + lhi * 4 + r) * STR + lcol]
                    = (bf16_t)(acc[fm][fn][r] + b);
    }
    __syncthreads();
    #pragma unroll
    for (int i = 0; i < 8; ++i) {
        const int q = tid + i * 256;
        const int row = q >> 4, ch = q & 15;
        *(uint4*)(Cout + (size_t)(m0 + row) * CVP2 + n0 + ch * 8)
            = *(const uint4*)&st[row * STR + ch * 8];
    }
}

// =======================================================================
// gate GEMM core (per-wave LDS, async staging, counted vmcnt)
// =======================================================================
__device__ __forceinline__ void gate_core(
    const bf16_t* __restrict__ A, int lda,
    const bf16_t* __restrict__ W, int ldw, int ktz, int kb, int n0,
    uint8_t (*sm)[2][6144], bf16_t* __restrict__ gp)
{
    const int tid = threadIdx.x;
    const int w = tid >> 6, lane = tid & 63;
    const int llo = lane & 15, lhi = lane >> 4;

    f32x4 acc0 = {0.f,0.f,0.f,0.f}, acc1 = {0.f,0.f,0.f,0.f};

    auto stage = [&](int buf, int ti) {
        const int k0 = (kb + ti) << 6;
        uint8_t* base = sm[w][buf];
        #pragma unroll
        for (int i = 0; i < 4; ++i) {
            const int q = lane + i * 64;
            const int row = q >> 3, c = q & 7;
            const int scz = c ^ (row & 7);
            const bf16_t* gpt = A + (size_t)(w * 32 + row) * lda + k0 + scz * 8;
            __builtin_amdgcn_global_load_lds((glb_u32*)gpt,
                (lds_u32*)(base + i * 1024 + lane * 16), 16, 0, 0);
        }
        #pragma unroll
        for (int i = 0; i < 2; ++i) {
            const int q = lane + i * 64;
            const int row = q >> 3, c = q & 7;
            const int scz = c ^ (row & 7);
            const bf16_t* gpt = W + (size_t)(n0 + row) * ldw + k0 + scz * 8;
            __builtin_amdgcn_global_load_lds((glb_u32*)gpt,
                (lds_u32*)(base + 4096 + i * 1024 + lane * 16), 16, 0, 0);
        }
    };
    auto compute = [&](int buf) {
        const uint8_t* base = sm[w][buf];
        const int r7 = llo & 7;
        #pragma unroll
        for (int kk = 0; kk < 2; ++kk) {
            const int coff = ((kk * 4 + lhi) ^ r7) << 4;
            bf16x8 a0 = *(const bf16x8*)(base + llo * 128 + coff);
            bf16x8 a1 = *(const bf16x8*)(base + (16 + llo) * 128 + coff);
            bf16x8 bb = *(const bf16x8*)(base + 4096 + llo * 128 + coff);
            acc0 = __builtin_amdgcn_mfma_f32_16x16x32_bf16(a0, bb, acc0, 0, 0, 0);
            acc1 = __builtin_amdgcn_mfma_f32_16x16x32_bf16(a1, bb, acc1, 0, 0, 0);
        }
    };

    stage(0, 0);
    if (ktz > 1) stage(1, 1);
    int cur = 0;
    for (int ti = 0; ti < ktz; ++ti) {
        if (ti + 1 < ktz) asm volatile("s_waitcnt vmcnt(6)" ::: "memory");
        else              asm volatile("s_waitcnt vmcnt(0)" ::: "memory");
        __builtin_amdgcn_sched_barrier(0);
        compute(cur);
        __builtin_amdgcn_sched_barrier(0);
        if (ti + 2 < ktz) stage(cur, ti + 2);
        cur ^= 1;
    }

    const int col = n0 + llo;
    #pragma unroll
    for (int r = 0; r < 4; ++r) {
        gp[(size_t)(w * 32 + lhi * 4 + r) * G4 + col] = (bf16_t)acc0[r];
        gp[(size_t)(w * 32 + 16 + lhi * 4 + r) * G4 + col] = (bf16_t)acc1[r];
    }
}

// arrival: returns rank (old count). release-fence before increment.
__device__ __forceinline__ int arrive(int* cnt, int* srank)
{
    __syncthreads();
    if (threadIdx.x == 0) {
        __threadfence();
        *srank = atomicAdd(cnt, 1);
    }
    __syncthreads();
    return *srank;
}

// coherent spin: device-scope atomic load (bypasses stale per-XCD L2 line)
__device__ __forceinline__ void spin_until(int* cnt, int target)
{
    if (threadIdx.x == 0) {
        while (__hip_atomic_load(cnt, __ATOMIC_RELAXED,
                                 __HIP_MEMORY_SCOPE_AGENT) < target)
            __builtin_amdgcn_s_sleep(2);
    }
    __syncthreads();
    __threadfence();   // acquire: invalidate L2 before reading gpart
}

// =======================================================================
// gate_att_fused: att gate partials + tail-fused {reduce, att-LSTM, hq,
// attention}. grid (256, 4); last 128 arrivals handle one batch row each.
// =======================================================================
__global__ __launch_bounds__(256)
void gate_att_fused(const bf16_t* __restrict__ A, const bf16_t* __restrict__ W,
                    bf16_t* __restrict__ gpart, int* __restrict__ cnt,
                    const bf16_t* __restrict__ gpre_fc, const bf16_t* __restrict__ gemb,
                    const float* __restrict__ cbias, float* __restrict__ c_att,
                    const bf16_t* __restrict__ p_att, const bf16_t* __restrict__ att_e,
                    const bf16_t* __restrict__ h2att_wT, const float* __restrict__ h2att_b,
                    const float* __restrict__ alpha_w, const float* __restrict__ alpha_b,
                    bf16_t* __restrict__ xh_nxt, bf16_t* __restrict__ xl_cur)
{
    __shared__ __align__(16) uint8_t sm[4][2][6144];
    __shared__ int srank;

    const int n0 = blockIdx.x * 16;
    const int z  = blockIdx.y;
    gate_core(A, XH, W, XH, 8, z * 8, n0, sm, gpart + (size_t)z * CB * G4);

    const int rank = arrive(cnt, &srank);
    if (rank < NGB - NTAIL) return;
    spin_until(cnt, NGB);
    const int b = rank - (NGB - NTAIL);
    const int tid = threadIdx.x;

    float* sh  = (float*)sm;
    float* shq = sh + CH;
    float* se  = shq + CAH;
    float* sal = se + 64;

    #pragma unroll
    for (int k4 = 0; k4 < 4; ++k4) {
        const int j = tid + k4 * 256;
        float g0 = 0.f, g1 = 0.f, g2 = 0.f, g3 = 0.f;
        #pragma unroll
        for (int zz = 0; zz < 4; ++zz) {
            bf16x4 g = *(const bf16x4*)(gpart + (size_t)zz * CB * G4 + (size_t)b * G4 + 4 * j);
            g0 += (float)g[0]; g1 += (float)g[1]; g2 += (float)g[2]; g3 += (float)g[3];
        }
        f32x4 cb = *(const f32x4*)(cbias + 4 * j);
        bf16x4 gf4 = *(const bf16x4*)(gpre_fc + (size_t)b * G4 + 4 * j);
        bf16x4 ge4 = *(const bf16x4*)(gemb + (size_t)b * G4 + 4 * j);
        const float gi = g0 + cb[0] + (float)gf4[0] + (float)ge4[0];
        const float gf = g1 + cb[1] + (float)gf4[1] + (float)ge4[1];
        const float gg = g2 + cb[2] + (float)gf4[2] + (float)ge4[2];
        const float go = g3 + cb[3] + (float)gf4[3] + (float)ge4[3];
        const float si = 1.f / (1.f + expf(-gi));
        const float sf = 1.f / (1.f + expf(-gf));
        const float so = 1.f / (1.f + expf(-go));
        const float cn = sf * c_att[b * CH + j] + si * tanhf(gg);
        const float hn = so * tanhf(cn);
        c_att[b * CH + j] = cn;
        sh[j] = hn;
        const bf16_t hb = (bf16_t)hn;
        xh_nxt[(size_t)b * XH + 1024 + j] = hb;
        xl_cur[(size_t)b * XL3 + 1024 + j] = hb;
    }
    __syncthreads();

    {   // hq with 4-lane k-split
        const int q4 = tid & 3;
        for (int n = tid >> 2; n < CAH; n += 64) {
            const bf16_t* wrow = h2att_wT + (size_t)n * CH + q4 * 256;
            float s = 0.f;
            #pragma unroll 4
            for (int k = 0; k < 256; k += 8) {
                bf16x8 w8 = *(const bf16x8*)(wrow + k);
                #pragma unroll
                for (int j = 0; j < 8; ++j) s = fmaf((float)w8[j], sh[q4 * 256 + k + j], s);
            }
            s += __shfl_xor(s, 1);
            s += __shfl_xor(s, 2);
            if (q4 == 0) shq[n] = s + h2att_b[n];
        }
    }
    __syncthreads();

    {   // e scores: 4 waves over 36 regions
        const int wave = tid >> 6, lane = tid & 63;
        for (int n = wave; n < CNREG; n += 4) {
            const bf16_t* pr = p_att + ((size_t)b * CNREG + n) * CAH;
            float s = 0.f;
            #pragma unroll
            for (int q = 0; q < CAH / 64; ++q) {
                const int d = lane + q * 64;
                s += alpha_w[d] * tanhf((float)pr[d] + shq[d]);
            }
            for (int off = 32; off; off >>= 1) s += __shfl_down(s, off);
            if (lane == 0) se[n] = s + alpha_b[0];
        }
    }
    __syncthreads();

    {
        float mx = -1e30f;
        for (int n = 0; n < CNREG; ++n) mx = fmaxf(mx, se[n]);
        float sum = 0.f;
        for (int n = 0; n < CNREG; ++n) sum += expf(se[n] - mx);
        if (tid < CNREG) sal[tid] = expf(se[tid] - mx) / sum;
    }
    __syncthreads();

    {   // PV: 4 cols per thread
        const int d0 = tid * 4;
        float a0 = 0.f, a1 = 0.f, a2 = 0.f, a3 = 0.f;
        const bf16_t* ae = att_e + (size_t)b * CNREG * CFE + d0;
        #pragma unroll 4
        for (int n = 0; n < CNREG; ++n) {
            bf16x4 v = *(const bf16x4*)(ae + (size_t)n * CFE);
            const float al = sal[n];
            a0 = fmaf(al, (float)v[0], a0);
            a1 = fmaf(al, (float)v[1], a1);
            a2 = fmaf(al, (float)v[2], a2);
            a3 = fmaf(al, (float)v[3], a3);
        }
        bf16x4 o = { (bf16_t)a0, (bf16_t)a1, (bf16_t)a2, (bf16_t)a3 };
        *(bf16x4*)(xl_cur + (size_t)b * XL3 + d0) = o;
    }
}

// =======================================================================
// gate_lang_fused: lang gate partials + tail-fused {reduce, lang-LSTM}.
// =======================================================================
__global__ __launch_bounds__(256)
void gate_lang_fused(const bf16_t* __restrict__ A, const bf16_t* __restrict__ W,
                     bf16_t* __restrict__ gpart, int* __restrict__ cnt,
                     const float* __restrict__ cbias, float* __restrict__ c,
                     bf16_t* __restrict__ xh_nxt, bf16_t* __restrict__ xl_nxt,
                     bf16_t* __restrict__ h_all, int t)
{
    __shared__ __align__(16) uint8_t sm[4][2][6144];
    __shared__ int srank;

    const int n0 = blockIdx.x * 16;
    const int z  = blockIdx.y;
    gate_core(A, XL3, W, XL3, 12, z * 12, n0, sm, gpart + (size_t)z * CB * G4);

    const int rank = arrive(cnt, &srank);
    if (rank < NGB - NTAIL) return;
    spin_until(cnt, NGB);
    const int b = rank - (NGB - NTAIL);
    const int tid = threadIdx.x;

    #pragma unroll
    for (int k4 = 0; k4 < 4; ++k4) {
        const int j = tid + k4 * 256;
        float g0 = 0.f, g1 = 0.f, g2 = 0.f, g3 = 0.f;
        #pragma unroll
        for (int zz = 0; zz < 4; ++zz) {
            bf16x4 g = *(const bf16x4*)(gpart + (size_t)zz * CB * G4 + (size_t)b * G4 + 4 * j);
            g0 += (float)g[0]; g1 += (float)g[1]; g2 += (float)g[2]; g3 += (float)g[3];
        }
        f32x4 cb = *(const f32x4*)(cbias + 4 * j);
        const float si = 1.f / (1.f + expf(-(g0 + cb[0])));
        const float sf = 1.f / (1.f + expf(-(g1 + cb[1])));
        const float so = 1.f / (1.f + expf(-(g3 + cb[3])));
        const float cn = sf * c[b * CH + j] + si * tanhf(g2 + cb[2]);
        const float hn = so * tanhf(cn);
        c[b * CH + j] = cn;
        const bf16_t hb = (bf16_t)hn;
        xh_nxt[(size_t)b * XH + j] = hb;
        xl_nxt[(size_t)b * XL3 + 2048 + j] = hb;
        h_all[((size_t)b * (CT - 1) + t) * CH + j] = hb;
    }
}

// ---------------- prep kernels ----------------
__global__ void convert_pad(const float* __restrict__ src, bf16_t* __restrict__ dst,
                            int C, int Cp)
{
    const int r = blockIdx.y;
    const int c = blockIdx.x * 256 + threadIdx.x;
    if (c >= Cp) return;
    dst[(size_t)r * Cp + c] = (c < C) ? (bf16_t)src[(size_t)r * C + c] : (bf16_t)0.f;
}

__global__ void convert_perm(const float* __restrict__ src, int srcld, int scol0,
                             int valid, bf16_t* __restrict__ dst, int dstld, int dcol0,
                             int ncols)
{
    const int rp = blockIdx.y;
    const int c = blockIdx.x * 256 + threadIdx.x;
    if (c >= ncols) return;
    const int rs = (rp & 3) * 1024 + (rp >> 2);
    const float v = (c < valid) ? src[(size_t)rs * srcld + scol0 + c] : 0.f;
    dst[(size_t)rp * dstld + dcol0 + c] = (bf16_t)v;
}

__global__ void bias_perm(const float* __restrict__ bih, const float* __restrict__ bhh,
                          float* __restrict__ dst)
{
    const int rp = blockIdx.x * 256 + threadIdx.x;
    if (rp >= G4) return;
    const int rs = (rp & 3) * 1024 + (rp >> 2);
    dst[rp] = bih[rs] + bhh[rs];
}

__global__ __launch_bounds__(256)
void transpose_convert(const float* __restrict__ src, bf16_t* __restrict__ dst,
                       int K, int N)
{
    __shared__ float tile[32][33];
    const int n0 = blockIdx.x * 32, k0 = blockIdx.y * 32;
    const int tx = threadIdx.x & 31, ty = threadIdx.x >> 5;
    #pragma unroll
    for (int i = 0; i < 4; ++i) {
        const int k = k0 + ty + i * 8, n = n0 + tx;
        tile[ty + i * 8][tx] = (k < K && n < N) ? src[(size_t)k * N + n] : 0.f;
    }
    __syncthreads();
    #pragma unroll
    for (int i = 0; i < 4; ++i) {
        const int n = n0 + ty + i * 8, k = k0 + tx;
        if (n < N && k < K) dst[(size_t)n * K + k] = (bf16_t)tile[tx][ty + i * 8];
    }
}

__global__ void emb_all(const float* __restrict__ emb_w,
                        const int* __restrict__ captions, bf16_t* __restrict__ w_emb)
{
    const int r = blockIdx.y;
    const int j = blockIdx.x * 256 + threadIdx.x;
    const int t = r >> 7, b = r & 127;
    const int tok = captions[b * CT + t];
    const float v = (j < CWE) ? fmaxf(emb_w[(size_t)tok * CWE + j], 0.f) : 0.f;
    w_emb[(size_t)r * 1024 + j] = (bf16_t)v;
}

// ---- log-softmax from bf16 logits [2048][CVP2] -> fp32 out [2048][CV] ----
__global__ __launch_bounds__(256)
void logsoftmax_bf(const bf16_t* __restrict__ lg, float* __restrict__ out)
{
    __shared__ float red[4];
    const int r = blockIdx.x, tid = threadIdx.x;
    const bf16_t* row = lg + (size_t)r * CVP2;

    float v[48];
    float mx = -1e30f;
    #pragma unroll
    for (int i = 0; i < 6; ++i) {
        const int c = tid + i * 256;
        if (c < 1500) {
            bf16x8 x = *(const bf16x8*)(row + c * 8);
            #pragma unroll
            for (int j = 0; j < 8; ++j) {
                v[i * 8 + j] = (float)x[j];
                mx = fmaxf(mx, v[i * 8 + j]);
            }
        } else {
            #pragma unroll
            for (int j = 0; j < 8; ++j) v[i * 8 + j] = -1e30f;
        }
    }
    for (int off = 32; off; off >>= 1) mx = fmaxf(mx, __shfl_down(mx, off));
    if ((tid & 63) == 0) red[tid >> 6] = mx;
    __syncthreads();
    mx = fmaxf(fmaxf(red[0], red[1]), fmaxf(red[2], red[3]));
    __syncthreads();

    float sum = 0.f;
    #pragma unroll
    for (int i = 0; i < 6; ++i)
        if (tid + i * 256 < 1500)
            #pragma unroll
            for (int j = 0; j < 8; ++j) sum += expf(v[i * 8 + j] - mx);
    for (int off = 32; off; off >>= 1) sum += __shfl_down(sum, off);
    if ((tid & 63) == 0) red[tid >> 6] = sum;
    __syncthreads();
    sum = red[0] + red[1] + red[2] + red[3];
    const float lse = mx + logf(sum);

    #pragma unroll
    for (int i = 0; i < 6; ++i) {
        const int c = tid + i * 256;
        if (c < 1500) {
            float* o = out + (size_t)r * CV + c * 8;
            float4 a = make_float4(v[i*8+0]-lse, v[i*8+1]-lse, v[i*8+2]-lse, v[i*8+3]-lse);
            float4 bq = make_float4(v[i*8+4]-lse, v[i*8+5]-lse, v[i*8+6]-lse, v[i*8+7]-lse);
            *(float4*)o = a;
            *(float4*)(o + 4) = bq;
        }
    }
}

// ---------------- launch ----------------
extern "C" void kernel_launch(void* const* d_in, const int* in_sizes, int n_in,
                              void* d_out, int out_size, void* d_ws, size_t ws_size,
                              hipStream_t stream)
{
    const float* fc_feats  = (const float*)d_in[0];
    const float* att_feats = (const float*)d_in[1];
    const int*   captions  = (const int*)  d_in[2];
    const float* emb_w     = (const float*)d_in[3];
    const float* fc_w      = (const float*)d_in[4];
    const float* fc_b      = (const float*)d_in[5];
    const float* atte_w    = (const float*)d_in[6];
    const float* atte_b    = (const float*)d_in[7];
    const float* ctx_w     = (const float*)d_in[8];
    const float* ctx_b     = (const float*)d_in[9];
    const float* attl_wih  = (const float*)d_in[10];
    const float* attl_whh  = (const float*)d_in[11];
    const float* attl_bih  = (const float*)d_in[12];
    const float* attl_bhh  = (const float*)d_in[13];
    const float* h2att_w   = (const float*)d_in[14];
    const float* h2att_b   = (const float*)d_in[15];
    const float* alpha_w   = (const float*)d_in[16];
    const float* alpha_b   = (const float*)d_in[17];
    const float* langl_wih = (const float*)d_in[18];
    const float* langl_whh = (const float*)d_in[19];
    const float* langl_bih = (const float*)d_in[20];
    const float* langl_bhh = (const float*)d_in[21];
    const float* cls_w     = (const float*)d_in[22];
    const float* cls_b     = (const float*)d_in[23];

    float* out = (float*)d_out;

    // ---- workspace layout ----
    char* p = (char*)d_ws;
    auto alloc_bf = [&](size_t e) { bf16_t* q = (bf16_t*)p; p += e * 2; return q; };
    auto alloc_f  = [&](size_t e) { float*  q = (float*) p; p += e * 4; return q; };

    bf16_t* Wcat_att    = alloc_bf((size_t)G4 * XH);
    bf16_t* Wcat_lang   = alloc_bf((size_t)G4 * XL3);
    bf16_t* Win_fc      = alloc_bf((size_t)G4 * 1024);
    bf16_t* Win_emb     = alloc_bf((size_t)G4 * 1024);
    bf16_t* fc_wT_b     = alloc_bf((size_t)CFE * CFEAT);
    bf16_t* atte_wT_b   = alloc_bf((size_t)CFE * CFEAT);
    bf16_t* ctx_wT_b    = alloc_bf((size_t)CAH * CFE);
    bf16_t* h2att_wT_b  = alloc_bf((size_t)CAH * CH);
    bf16_t* cls_wT_b    = alloc_bf((size_t)CVP2 * CH);
    bf16_t* fc_feats_b  = alloc_bf((size_t)CB * CFEAT);
    bf16_t* att_feats_b = alloc_bf((size_t)CB * CNREG * CFEAT);  // Gemb aliases
    bf16_t* att_e_b     = alloc_bf((size_t)CB * CNREG * CFE);
    bf16_t* w_emb       = alloc_bf((size_t)(CT - 1) * CB * 1024);
    bf16_t* fc_e_b      = alloc_bf((size_t)CB * CFE);
    bf16_t* gpre_fc     = alloc_bf((size_t)CB * G4);
    bf16_t* xh0         = alloc_bf((size_t)CB * XH);
    bf16_t* xh1         = alloc_bf((size_t)CB * XH);
    bf16_t* xl3a        = alloc_bf((size_t)CB * XL3);
    bf16_t* xl3b        = alloc_bf((size_t)CB * XL3);
    bf16_t* h_all       = alloc_bf((size_t)CB * (CT - 1) * CH);
    bf16_t* p_att       = alloc_bf((size_t)CB * CNREG * CAH);
    bf16_t* gpart       = alloc_bf((size_t)4 * CB * G4);
    float*  cbias_att   = alloc_f (G4);
    float*  cbias_lang  = alloc_f (G4);
    float*  c_att       = alloc_f ((size_t)CB * CH);
    float*  c_lang      = alloc_f ((size_t)CB * CH);
    int*    counters    = (int*)p; p += 64 * sizeof(int);

    bf16_t* Gemb   = att_feats_b;
    bf16_t* logits = Wcat_att;     // dead after loop; 50.33MB exact fit

    // ---- zero state + counters (every launch; graph-replay safe) ----
    hipMemsetAsync(xh0,    0, (size_t)CB * XH * 2, stream);
    hipMemsetAsync(xh1,    0, (size_t)CB * XH * 2, stream);
    hipMemsetAsync(xl3a,   0, (size_t)CB * XL3 * 2, stream);
    hipMemsetAsync(xl3b,   0, (size_t)CB * XL3 * 2, stream);
    hipMemsetAsync(c_att,  0, (size_t)CB * CH * 4, stream);
    hipMemsetAsync(c_lang, 0, (size_t)CB * CH * 4, stream);
    hipMemsetAsync(cls_wT_b + (size_t)CV * CH, 0, (size_t)(CVP2 - CV) * CH * 2, stream);
    hipMemsetAsync(counters, 0, 64 * sizeof(int), stream);

    const dim3 blk(256);
    auto mk = [](const bf16_t* A, int lda, const bf16_t* W, int ldw, int kt) {
        return Seg{A, W, lda, ldw, kt};
    };

    // ---- one-time weight prep ----
    convert_perm<<<dim3(4, G4), blk, 0, stream>>>(attl_wih, 3048, 0, 1024, Wcat_att, XH, 0, 1024);
    convert_perm<<<dim3(4, G4), blk, 0, stream>>>(attl_whh, 1024, 0, 1024, Wcat_att, XH, 1024, 1024);
    convert_perm<<<dim3(4, G4), blk, 0, stream>>>(attl_wih, 3048, 1024, 1024, Win_fc, 1024, 0, 1024);
    convert_perm<<<dim3(4, G4), blk, 0, stream>>>(attl_wih, 3048, 2048, 1000, Win_emb, 1024, 0, 1024);
    convert_perm<<<dim3(8, G4), blk, 0, stream>>>(langl_wih, 2048, 0, 2048, Wcat_lang, XL3, 0, 2048);
    convert_perm<<<dim3(4, G4), blk, 0, stream>>>(langl_whh, 1024, 0, 1024, Wcat_lang, XL3, 2048, 1024);
    bias_perm<<<16, blk, 0, stream>>>(attl_bih, attl_bhh, cbias_att);
    bias_perm<<<16, blk, 0, stream>>>(langl_bih, langl_bhh, cbias_lang);
    convert_pad<<<dim3(8, CB), blk, 0, stream>>>(fc_feats, fc_feats_b, CFEAT, CFEAT);
    convert_pad<<<dim3(8, CB * CNREG), blk, 0, stream>>>(att_feats, att_feats_b, CFEAT, CFEAT);
    transpose_convert<<<dim3(CFE/32, CFEAT/32), blk, 0, stream>>>(fc_w,    fc_wT_b,    CFEAT, CFE);
    transpose_convert<<<dim3(CFE/32, CFEAT/32), blk, 0, stream>>>(atte_w,  atte_wT_b,  CFEAT, CFE);
    transpose_convert<<<dim3(CAH/32, CFE/32),   blk, 0, stream>>>(ctx_w,   ctx_wT_b,   CFE,   CAH);
    transpose_convert<<<dim3(CAH/32, CH/32),    blk, 0, stream>>>(h2att_w, h2att_wT_b, CH,    CAH);
    transpose_convert<<<dim3(CDIV(CV,32), CH/32), blk, 0, stream>>>(cls_w, cls_wT_b,   CH,    CV);
    emb_all<<<dim3(4, (CT - 1) * CB), blk, 0, stream>>>(emb_w, captions, w_emb);

    // ---- preamble GEMMs ----
    pre_gemm<true,true,2><<<16, blk, 0, stream>>>(
        mk(fc_feats_b, CFEAT, fc_wT_b, CFEAT, 32), 16, fc_b, fc_e_b, CFE);
    pre_gemm<true,true,2><<<576, blk, 0, stream>>>(
        mk(att_feats_b, CFEAT, atte_wT_b, CFEAT, 32), 16, atte_b, att_e_b, CFE);
    pre_gemm<false,true,2><<<288, blk, 0, stream>>>(
        mk(att_e_b, CFE, ctx_wT_b, CFE, 16), 8, ctx_b, p_att, CAH);
    pre_gemm<false,true,1><<<64, blk, 0, stream>>>(
        mk(fc_e_b, CFE, Win_fc, 1024, 16), 1, nullptr, gpre_fc, G4);
    pre_gemm<false,true,3><<<1024, blk, 0, stream>>>(
        mk(w_emb, 1024, Win_emb, 1024, 16), 0, nullptr, Gemb, G4);

    // ---- recurrence: 2 launches per step (tail-fused pointwise) ----
    for (int t = 0; t < CT - 1; ++t) {
        bf16_t* xh_cur = (t & 1) ? xh1 : xh0;
        bf16_t* xh_nxt = (t & 1) ? xh0 : xh1;
        bf16_t* xl_cur = (t & 1) ? xl3b : xl3a;
        bf16_t* xl_nxt = (t & 1) ? xl3a : xl3b;

        gate_att_fused<<<dim3(256, 4), blk, 0, stream>>>(
            xh_cur, Wcat_att, gpart, counters + t * 2,
            gpre_fc, Gemb + (size_t)t * CB * G4, cbias_att, c_att,
            p_att, att_e_b, h2att_wT_b, h2att_b, alpha_w, alpha_b,
            xh_nxt, xl_cur);

        gate_lang_fused<<<dim3(256, 4), blk, 0, stream>>>(
            xl_cur, Wcat_lang, gpart, counters + t * 2 + 1,
            cbias_lang, c_lang, xh_nxt, xl_nxt, h_all, t);
    }

    // ---- deferred classifier + log-softmax ----
    cls_gemm<<<1536, blk, 0, stream>>>(h_all, cls_wT_b, cls_b, logits);
    logsoftmax_bf<<<2048, blk, 0, stream>>>(logits, out);
}

// Round 18
// 1907.532 us; speedup vs baseline: 2.2811x; 2.2811x over previous
//
#include <hip/hip_runtime.h>
#include <cstddef>
#include <cstdint>

// ---------------- problem constants ----------------
constexpr int CV    = 12000;
constexpr int CVP2  = 12288;   // vocab padded to 96 n-tiles of 128
constexpr int CWE   = 1000;
constexpr int CFEAT = 2048;
constexpr int CFE   = 1024;
constexpr int CH    = 1024;
constexpr int CAH   = 512;
constexpr int CNREG = 36;
constexpr int CB    = 128;
constexpr int CT    = 17;
constexpr int G4    = 4096;
constexpr int XH    = 2048;    // xh  = [h_lang | h_att]
constexpr int XL3   = 3072;    // xl3 = [att_res | h_att | h_lang_prev]

#define CDIV(a,b) (((a)+(b)-1)/(b))

typedef __bf16 bf16_t;
typedef __bf16 bf16x8 __attribute__((ext_vector_type(8)));
typedef __bf16 bf16x4 __attribute__((ext_vector_type(4)));
typedef float  f32x4  __attribute__((ext_vector_type(4)));

typedef __attribute__((address_space(3))) uint32_t lds_u32;
typedef const __attribute__((address_space(1))) uint32_t glb_u32;

struct Seg { const bf16_t* A; const bf16_t* W; int lda, ldw, kt; };

// =======================================================================
// pre_gemm: C = A @ W^T + b. BM=128, BN=64, BK=64.
// SWZ=1 n-slow, SWZ=2 m-slow, SWZ=3 2D chunks (2m x 4n XCDs; 16m x 64n grid).
// OUTBF: LDS-staged bf16 epilogue (full-line stores).
// =======================================================================
template<bool RELU, bool OUTBF, int SWZ>
__global__ __launch_bounds__(256)
void pre_gemm(Seg s0, int inner, const float* __restrict__ bias1,
              void* __restrict__ Cout, int ldc)
{
    const int tid = threadIdx.x;
    const int wid = tid >> 6, lane = tid & 63;
    const int wr = wid >> 1, wc = wid & 1;
    const int llo = lane & 15, lhi = lane >> 4;
    const int nb = gridDim.x, id = blockIdx.x;
    const int sw = (id & 7) * (nb >> 3) + (id >> 3);
    int m0, n0;
    if (SWZ == 1)      { n0 = (sw / inner) * 64;  m0 = (sw % inner) * 128; }
    else if (SWZ == 2) { m0 = (sw / inner) * 128; n0 = (sw % inner) * 64;  }
    else {  // 2D: 8 XCDs as 2(m) x 4(n); chunk = 8 m-tiles x 16 n-tiles
        const int xcd = id & 7, idx = id >> 3;
        m0 = (((xcd >> 2) << 3) + (idx & 7)) * 128;
        n0 = (((xcd & 3) << 4) + (idx >> 3)) * 64;
    }

    __shared__ __align__(16) uint8_t sm[2][24576];

    const int TT = s0.kt;
    f32x4 acc[4][2] = {};
    uint4 ra[4], rb[2];
    const int srow = tid >> 3, sc = tid & 7;
    const int cswz = (sc ^ (srow & 7)) << 4;

    auto load_tile = [&](int ti) {
        const int k0 = ti << 6;
        #pragma unroll
        for (int i = 0; i < 4; ++i)
            ra[i] = *(const uint4*)(s0.A + (size_t)(m0 + i * 32 + srow) * s0.lda + k0 + sc * 8);
        #pragma unroll
        for (int i = 0; i < 2; ++i)
            rb[i] = *(const uint4*)(s0.W + (size_t)(n0 + i * 32 + srow) * s0.ldw + k0 + sc * 8);
    };
    auto write_tile = [&](int buf) {
        uint8_t* base = sm[buf];
        #pragma unroll
        for (int i = 0; i < 4; ++i) *(uint4*)(base + (i * 32 + srow) * 128 + cswz) = ra[i];
        #pragma unroll
        for (int i = 0; i < 2; ++i) *(uint4*)(base + 16384 + (i * 32 + srow) * 128 + cswz) = rb[i];
    };
    auto compute = [&](int buf) {
        const uint8_t* base = sm[buf];
        const int r7 = llo & 7;
        #pragma unroll
        for (int kk = 0; kk < 2; ++kk) {
            const int coff = ((kk * 4 + lhi) ^ r7) << 4;
            bf16x8 af[4], bg[2];
            #pragma unroll
            for (int fm = 0; fm < 4; ++fm)
                af[fm] = *(const bf16x8*)(base + (wr * 64 + fm * 16 + llo) * 128 + coff);
            #pragma unroll
            for (int fn = 0; fn < 2; ++fn)
                bg[fn] = *(const bf16x8*)(base + 16384 + (wc * 32 + fn * 16 + llo) * 128 + coff);
            #pragma unroll
            for (int fm = 0; fm < 4; ++fm)
                #pragma unroll
                for (int fn = 0; fn < 2; ++fn)
                    acc[fm][fn] = __builtin_amdgcn_mfma_f32_16x16x32_bf16(
                        af[fm], bg[fn], acc[fm][fn], 0, 0, 0);
        }
    };

    load_tile(0); write_tile(0);
    load_tile(1);
    __syncthreads();
    int cur = 0;
    for (int ti = 0; ti < TT; ++ti) {
        if (ti + 1 < TT) write_tile(cur ^ 1);
        if (ti + 2 < TT) load_tile(ti + 2);
        compute(cur);
        __syncthreads();
        cur ^= 1;
    }

    if (OUTBF) {
        bf16_t* st = (bf16_t*)sm[0];
        #pragma unroll
        for (int fn = 0; fn < 2; ++fn) {
            const int lcol = wc * 32 + fn * 16 + llo;
            const float b = bias1 ? bias1[n0 + lcol] : 0.f;
            #pragma unroll
            for (int fm = 0; fm < 4; ++fm)
                #pragma unroll
                for (int r = 0; r < 4; ++r) {
                    float v = acc[fm][fn][r] + b;
                    if (RELU) v = fmaxf(v, 0.f);
                    st[(wr * 64 + fm * 16 + lhi * 4 + r) * 64 + lcol] = (bf16_t)v;
                }
        }
        __syncthreads();
        #pragma unroll
        for (int i = 0; i < 4; ++i) {
            const int q = tid + i * 256;
            const int row = q >> 3, ch = q & 7;
            *(uint4*)((bf16_t*)Cout + (size_t)(m0 + row) * ldc + n0 + ch * 8)
                = *(const uint4*)&st[row * 64 + ch * 8];
        }
    } else {
        const int colb = n0 + wc * 32;
        const int rowb = m0 + wr * 64 + lhi * 4;
        #pragma unroll
        for (int fn = 0; fn < 2; ++fn) {
            const int col = colb + fn * 16 + llo;
            const float b = bias1 ? bias1[col] : 0.f;
            #pragma unroll
            for (int fm = 0; fm < 4; ++fm)
                #pragma unroll
                for (int r = 0; r < 4; ++r) {
                    float v = acc[fm][fn][r] + b;
                    if (RELU) v = fmaxf(v, 0.f);
                    ((float*)Cout)[(size_t)(rowb + fm * 16 + r) * ldc + col] = v;
                }
        }
    }
}

// =======================================================================
// cls_gemm: A[2048,1024] @ W[12288,1024]^T + b -> bf16 logits [2048][CVP2].
// BM=128, BN=128, BK=64. XCD chunking 2m x 4n, m-fast-8 within chunk
// (co-resident set = A-half 2MB + 8 W-tiles 2MB ~ L2). Grid 1536.
// =======================================================================
__global__ __launch_bounds__(256)
void cls_gemm(const bf16_t* __restrict__ A, const bf16_t* __restrict__ W,
              const float* __restrict__ bias, bf16_t* __restrict__ Cout)
{
    const int tid = threadIdx.x;
    const int wid = tid >> 6, lane = tid & 63;
    const int wr = wid >> 1, wc = wid & 1;
    const int llo = lane & 15, lhi = lane >> 4;
    const int id = blockIdx.x;
    const int xcd = id & 7, idx = id >> 3;       // idx 0..191
    const int mg = xcd & 1, ng = xcd >> 1;       // 2m x 4n groups
    const int m0 = (mg * 8 + (idx & 7)) * 128;   // 16 m-tiles
    const int n0 = (ng * 24 + (idx >> 3)) * 128; // 96 n-tiles

    __shared__ __align__(16) uint8_t pool[65536];
    auto bufA = [&](int b) { return pool + b * 16384; };
    auto bufB = [&](int b) { return pool + 32768 + b * 16384; };

    constexpr int TT = 16;
    f32x4 acc[4][4] = {};
    uint4 ra[4], rbv[4];

    auto load_tile = [&](int ti) {
        const int k0 = ti << 6;
        #pragma unroll
        for (int i = 0; i < 4; ++i) {
            const int q = tid + i * 256;
            const int row = q >> 3, c = q & 7;
            ra[i]  = *(const uint4*)(A + (size_t)(m0 + row) * CH + k0 + c * 8);
            rbv[i] = *(const uint4*)(W + (size_t)(n0 + row) * CH + k0 + c * 8);
        }
    };
    auto write_tile = [&](int buf) {
        #pragma unroll
        for (int i = 0; i < 4; ++i) {
            const int q = tid + i * 256;
            const int row = q >> 3, c = q & 7;
            const int o = row * 128 + ((c ^ (row & 7)) << 4);
            *(uint4*)(bufA(buf) + o) = ra[i];
            *(uint4*)(bufB(buf) + o) = rbv[i];
        }
    };
    auto compute = [&](int buf) {
        const int r7 = llo & 7;
        #pragma unroll
        for (int kk = 0; kk < 2; ++kk) {
            const int coff = ((kk * 4 + lhi) ^ r7) << 4;
            bf16x8 af[4], bg[4];
            #pragma unroll
            for (int fm = 0; fm < 4; ++fm)
                af[fm] = *(const bf16x8*)(bufA(buf) + (wr * 64 + fm * 16 + llo) * 128 + coff);
            #pragma unroll
            for (int fn = 0; fn < 4; ++fn)
                bg[fn] = *(const bf16x8*)(bufB(buf) + (wc * 64 + fn * 16 + llo) * 128 + coff);
            #pragma unroll
            for (int fm = 0; fm < 4; ++fm)
                #pragma unroll
                for (int fn = 0; fn < 4; ++fn)
                    acc[fm][fn] = __builtin_amdgcn_mfma_f32_16x16x32_bf16(
                        af[fm], bg[fn], acc[fm][fn], 0, 0, 0);
        }
    };

    load_tile(0); write_tile(0);
    load_tile(1);
    __syncthreads();
    int cur = 0;
    for (int ti = 0; ti < TT; ++ti) {
        if (ti + 1 < TT) write_tile(cur ^ 1);
        if (ti + 2 < TT) load_tile(ti + 2);
        compute(cur);
        __syncthreads();
        cur ^= 1;
    }

    bf16_t* st = (bf16_t*)pool;   // [128][128] bf16
    #pragma unroll
    for (int fn = 0; fn < 4; ++fn) {
        const int lcol = wc * 64 + fn * 16 + llo;
        const int col = n0 + lcol;
        const float b = (col < CV) ? bias[col] : 0.f;
        #pragma unroll
        for (int fm = 0; fm < 4; ++fm)
            #pragma unroll
            for (int r = 0; r < 4; ++r)
                st[(wr * 64 + fm * 16 + lhi * 4 + r) * 128 + lcol]
                    = (bf16_t)(acc[fm][fn][r] + b);
    }
    __syncthreads();
    #pragma unroll
    for (int i = 0; i < 8; ++i) {
        const int q = tid + i * 256;
        const int row = q >> 4, ch = q & 15;
        *(uint4*)(Cout + (size_t)(m0 + row) * CVP2 + n0 + ch * 8)
            = *(const uint4*)&st[row * 128 + ch * 8];
    }
}

// =======================================================================
// gate_split: split-K gate GEMM partials (bf16). Tile 128x16, BK=64,
// grid (256 n-tiles, 4 z). Async global_load_lds staging, pre-swizzled
// source. W rows gate-permuted (r' = 4j+gate).
// =======================================================================
template<int TAG>
__global__ __launch_bounds__(256)
void gate_split(const bf16_t* __restrict__ A, int lda,
                const bf16_t* __restrict__ W, int ldw, int ktz,
                bf16_t* __restrict__ gpart)
{
    const int tid = threadIdx.x;
    const int w = tid >> 6, lane = tid & 63;
    const int llo = lane & 15, lhi = lane >> 4;
    const int n0 = blockIdx.x * 16;
    const int z  = blockIdx.y;
    const int kb = z * ktz;

    __shared__ __align__(16) uint8_t smA[2][16384];   // 128 rows x 128B
    __shared__ __align__(16) uint8_t smB[2][2048];    // 16 rows x 128B

    f32x4 acc0 = {0.f,0.f,0.f,0.f}, acc1 = {0.f,0.f,0.f,0.f};

    const int arow = tid >> 3, ac = tid & 7;
    const int asc = ac ^ (arow & 7);
    const int wvoff = (tid >> 6) * 1024;

    auto stage = [&](int buf, int ti) {
        const int k0 = (kb + ti) << 6;
        #pragma unroll
        for (int i = 0; i < 4; ++i) {
            const bf16_t* gp = A + (size_t)(arow + i * 32) * lda + k0 + asc * 8;
            __builtin_amdgcn_global_load_lds((glb_u32*)gp,
                (lds_u32*)(smA[buf] + i * 4096 + wvoff), 16, 0, 0);
        }
        if (tid < 128) {
            const int brow = tid >> 3, bc = tid & 7;
            const int bsc = bc ^ (brow & 7);
            const bf16_t* gp = W + (size_t)(n0 + brow) * ldw + k0 + bsc * 8;
            __builtin_amdgcn_global_load_lds((glb_u32*)gp,
                (lds_u32*)(smB[buf] + wvoff), 16, 0, 0);
        }
    };
    auto compute = [&](int buf) {
        const int r7 = llo & 7;
        #pragma unroll
        for (int kk = 0; kk < 2; ++kk) {
            const int coff = ((kk * 4 + lhi) ^ r7) << 4;
            bf16x8 a0 = *(const bf16x8*)(smA[buf] + (w * 32 + llo) * 128 + coff);
            bf16x8 a1 = *(const bf16x8*)(smA[buf] + (w * 32 + 16 + llo) * 128 + coff);
            bf16x8 bb = *(const bf16x8*)(smB[buf] + llo * 128 + coff);
            acc0 = __builtin_amdgcn_mfma_f32_16x16x32_bf16(a0, bb, acc0, 0, 0, 0);
            acc1 = __builtin_amdgcn_mfma_f32_16x16x32_bf16(a1, bb, acc1, 0, 0, 0);
        }
    };

    stage(0, 0);
    __syncthreads();
    int cur = 0;
    for (int ti = 0; ti < ktz; ++ti) {
        if (ti + 1 < ktz) stage(cur ^ 1, ti + 1);
        compute(cur);
        __syncthreads();
        cur ^= 1;
    }

    bf16_t* gp = gpart + (size_t)z * CB * G4;
    const int col = n0 + llo;
    #pragma unroll
    for (int r = 0; r < 4; ++r) {
        gp[(size_t)(w * 32 + lhi * 4 + r) * G4 + col] = (bf16_t)acc0[r];
        gp[(size_t)(w * 32 + 16 + lhi * 4 + r) * G4 + col] = (bf16_t)acc1[r];
    }
}

// =======================================================================
// lstm_attn: 1024 threads. reduce 4 bf16 partials + cbias + gpre_fc + gemb
// -> att-LSTM -> hq -> attention (p_att bf16). block b owns batch row b.
// =======================================================================
__global__ __launch_bounds__(1024)
void lstm_attn(const bf16_t* __restrict__ gpart, const bf16_t* __restrict__ gpre_fc,
               const bf16_t* __restrict__ gemb,
               const float* __restrict__ cbias, float* __restrict__ c_att,
               const bf16_t* __restrict__ p_att, const bf16_t* __restrict__ att_e,
               const bf16_t* __restrict__ h2att_wT, const float* __restrict__ h2att_b,
               const float* __restrict__ alpha_w, const float* __restrict__ alpha_b,
               bf16_t* __restrict__ xh_nxt, bf16_t* __restrict__ xl_cur)
{
    __shared__ float sh[CH];
    __shared__ float shq[CAH];
    __shared__ float se[64], salpha[64];
    const int b = blockIdx.x, tid = threadIdx.x;   // 0..1023

    {   // phase 1: reduce + LSTM cell; j = tid
        const int j = tid;
        float g0 = 0.f, g1 = 0.f, g2 = 0.f, g3 = 0.f;
        #pragma unroll
        for (int z = 0; z < 4; ++z) {
            bf16x4 g = *(const bf16x4*)(gpart + (size_t)z * CB * G4 + (size_t)b * G4 + 4 * j);
            g0 += (float)g[0]; g1 += (float)g[1]; g2 += (float)g[2]; g3 += (float)g[3];
        }
        f32x4 cb = *(const f32x4*)(cbias + 4 * j);
        bf16x4 gf4 = *(const bf16x4*)(gpre_fc + (size_t)b * G4 + 4 * j);
        bf16x4 ge4 = *(const bf16x4*)(gemb + (size_t)b * G4 + 4 * j);
        const float gi = g0 + cb[0] + (float)gf4[0] + (float)ge4[0];
        const float gf = g1 + cb[1] + (float)gf4[1] + (float)ge4[1];
        const float gg = g2 + cb[2] + (float)gf4[2] + (float)ge4[2];
        const float go = g3 + cb[3] + (float)gf4[3] + (float)ge4[3];
        const float si = 1.f / (1.f + expf(-gi));
        const float sf = 1.f / (1.f + expf(-gf));
        const float so = 1.f / (1.f + expf(-go));
        const float cn = sf * c_att[b * CH + j] + si * tanhf(gg);
        const float hn = so * tanhf(cn);
        c_att[b * CH + j] = cn;
        sh[j] = hn;
        const bf16_t hb = (bf16_t)hn;
        xh_nxt[(size_t)b * XH + 1024 + j] = hb;
        xl_cur[(size_t)b * XL3 + 1024 + j] = hb;
    }
    __syncthreads();

    {   // phase 2: hq; n = tid>>1, 2-lane k-split of 1024
        const int q2 = tid & 1, n = tid >> 1;
        const bf16_t* wrow = h2att_wT + (size_t)n * CH + q2 * 512;
        float s = 0.f;
        #pragma unroll 4
        for (int k = 0; k < 512; k += 8) {
            bf16x8 w8 = *(const bf16x8*)(wrow + k);
            #pragma unroll
            for (int j = 0; j < 8; ++j) s = fmaf((float)w8[j], sh[q2 * 512 + k + j], s);
        }
        s += __shfl_xor(s, 1);
        if (q2 == 0) shq[n] = s + h2att_b[n];
    }
    __syncthreads();

    {   // phase 3: e scores; 16 waves handle 36 regions
        const int wave = tid >> 6, lane = tid & 63;
        for (int n = wave; n < CNREG; n += 16) {
            const bf16_t* pr = p_att + ((size_t)b * CNREG + n) * CAH;
            float s = 0.f;
            #pragma unroll
            for (int q = 0; q < CAH / 64; ++q) {
                const int d = lane + q * 64;
                s += alpha_w[d] * tanhf((float)pr[d] + shq[d]);
            }
            for (int off = 32; off; off >>= 1) s += __shfl_down(s, off);
            if (lane == 0) se[n] = s + alpha_b[0];
        }
    }
    __syncthreads();

    {   // phase 4: softmax over 36 (replicated per thread; cheap)
        float mx = -1e30f;
        for (int n = 0; n < CNREG; ++n) mx = fmaxf(mx, se[n]);
        float sum = 0.f;
        for (int n = 0; n < CNREG; ++n) sum += expf(se[n] - mx);
        if (tid < CNREG) salpha[tid] = expf(se[tid] - mx) / sum;
    }
    __syncthreads();

    {   // phase 5: PV; d = tid, coalesced row reads
        const int d = tid;
        float s = 0.f;
        const bf16_t* ae = att_e + (size_t)b * CNREG * CFE + d;
        #pragma unroll 4
        for (int n = 0; n < CNREG; ++n)
            s = fmaf(salpha[n], (float)ae[(size_t)n * CFE], s);
        xl_cur[(size_t)b * XL3 + d] = (bf16_t)s;
    }
}

// ---- lstm_flat: reduce 4 bf16 partials + cbias -> lang-LSTM -> h_lang x3 ----
__global__ __launch_bounds__(256)
void lstm_flat(const bf16_t* __restrict__ gpart, const float* __restrict__ cbias,
               float* __restrict__ c,
               bf16_t* __restrict__ xh_nxt, bf16_t* __restrict__ xl_nxt,
               bf16_t* __restrict__ h_all, int t)
{
    const int idx = blockIdx.x * 256 + threadIdx.x;
    const int b = idx >> 10, j = idx & 1023;
    float g0 = 0.f, g1 = 0.f, g2 = 0.f, g3 = 0.f;
    #pragma unroll
    for (int z = 0; z < 4; ++z) {
        bf16x4 g = *(const bf16x4*)(gpart + (size_t)z * CB * G4 + (size_t)b * G4 + 4 * j);
        g0 += (float)g[0]; g1 += (float)g[1]; g2 += (float)g[2]; g3 += (float)g[3];
    }
    f32x4 cb = *(const f32x4*)(cbias + 4 * j);
    const float si = 1.f / (1.f + expf(-(g0 + cb[0])));
    const float sf = 1.f / (1.f + expf(-(g1 + cb[1])));
    const float so = 1.f / (1.f + expf(-(g3 + cb[3])));
    const float cn = sf * c[idx] + si * tanhf(g2 + cb[2]);
    const float hn = so * tanhf(cn);
    c[idx] = cn;
    const bf16_t hb = (bf16_t)hn;
    xh_nxt[(size_t)b * XH + j] = hb;
    xl_nxt[(size_t)b * XL3 + 2048 + j] = hb;
    h_all[((size_t)b * (CT - 1) + t) * CH + j] = hb;
}

// ---------------- prep kernels ----------------
__global__ void convert_pad(const float* __restrict__ src, bf16_t* __restrict__ dst,
                            int C, int Cp)
{
    const int r = blockIdx.y;
    const int c = blockIdx.x * 256 + threadIdx.x;
    if (c >= Cp) return;
    dst[(size_t)r * Cp + c] = (c < C) ? (bf16_t)src[(size_t)r * C + c] : (bf16_t)0.f;
}

__global__ void convert_perm(const float* __restrict__ src, int srcld, int scol0,
                             int valid, bf16_t* __restrict__ dst, int dstld, int dcol0,
                             int ncols)
{
    const int rp = blockIdx.y;
    const int c = blockIdx.x * 256 + threadIdx.x;
    if (c >= ncols) return;
    const int rs = (rp & 3) * 1024 + (rp >> 2);
    const float v = (c < valid) ? src[(size_t)rs * srcld + scol0 + c] : 0.f;
    dst[(size_t)rp * dstld + dcol0 + c] = (bf16_t)v;
}

__global__ void bias_perm(const float* __restrict__ bih, const float* __restrict__ bhh,
                          float* __restrict__ dst)
{
    const int rp = blockIdx.x * 256 + threadIdx.x;
    if (rp >= G4) return;
    const int rs = (rp & 3) * 1024 + (rp >> 2);
    dst[rp] = bih[rs] + bhh[rs];
}

__global__ __launch_bounds__(256)
void transpose_convert(const float* __restrict__ src, bf16_t* __restrict__ dst,
                       int K, int N)
{
    __shared__ float tile[32][33];
    const int n0 = blockIdx.x * 32, k0 = blockIdx.y * 32;
    const int tx = threadIdx.x & 31, ty = threadIdx.x >> 5;
    #pragma unroll
    for (int i = 0; i < 4; ++i) {
        const int k = k0 + ty + i * 8, n = n0 + tx;
        tile[ty + i * 8][tx] = (k < K && n < N) ? src[(size_t)k * N + n] : 0.f;
    }
    __syncthreads();
    #pragma unroll
    for (int i = 0; i < 4; ++i) {
        const int n = n0 + ty + i * 8, k = k0 + tx;
        if (n < N && k < K) dst[(size_t)n * K + k] = (bf16_t)tile[tx][ty + i * 8];
    }
}

__global__ void emb_all(const float* __restrict__ emb_w,
                        const int* __restrict__ captions, bf16_t* __restrict__ w_emb)
{
    const int r = blockIdx.y;
    const int j = blockIdx.x * 256 + threadIdx.x;
    const int t = r >> 7, b = r & 127;
    const int tok = captions[b * CT + t];
    const float v = (j < CWE) ? fmaxf(emb_w[(size_t)tok * CWE + j], 0.f) : 0.f;
    w_emb[(size_t)r * 1024 + j] = (bf16_t)v;
}

// ---- log-softmax from bf16 logits [2048][CVP2] -> fp32 out [2048][CV] ----
__global__ __launch_bounds__(256)
void logsoftmax_bf(const bf16_t* __restrict__ lg, float* __restrict__ out)
{
    __shared__ float red[4];
    const int r = blockIdx.x, tid = threadIdx.x;
    const bf16_t* row = lg + (size_t)r * CVP2;

    float v[48];
    float mx = -1e30f;
    #pragma unroll
    for (int i = 0; i < 6; ++i) {
        const int c = tid + i * 256;
        if (c < 1500) {
            bf16x8 x = *(const bf16x8*)(row + c * 8);
            #pragma unroll
            for (int j = 0; j < 8; ++j) {
                v[i * 8 + j] = (float)x[j];
                mx = fmaxf(mx, v[i * 8 + j]);
            }
        } else {
            #pragma unroll
            for (int j = 0; j < 8; ++j) v[i * 8 + j] = -1e30f;
        }
    }
    for (int off = 32; off; off >>= 1) mx = fmaxf(mx, __shfl_down(mx, off));
    if ((tid & 63) == 0) red[tid >> 6] = mx;
    __syncthreads();
    mx = fmaxf(fmaxf(red[0], red[1]), fmaxf(red[2], red[3]));
    __syncthreads();

    float sum = 0.f;
    #pragma unroll
    for (int i = 0; i < 6; ++i)
        if (tid + i * 256 < 1500)
            #pragma unroll
            for (int j = 0; j < 8; ++j) sum += expf(v[i * 8 + j] - mx);
    for (int off = 32; off; off >>= 1) sum += __shfl_down(sum, off);
    if ((tid & 63) == 0) red[tid >> 6] = sum;
    __syncthreads();
    sum = red[0] + red[1] + red[2] + red[3];
    const float lse = mx + logf(sum);

    #pragma unroll
    for (int i = 0; i < 6; ++i) {
        const int c = tid + i * 256;
        if (c < 1500) {
            float* o = out + (size_t)r * CV + c * 8;
            float4 a = make_float4(v[i*8+0]-lse, v[i*8+1]-lse, v[i*8+2]-lse, v[i*8+3]-lse);
            float4 bq = make_float4(v[i*8+4]-lse, v[i*8+5]-lse, v[i*8+6]-lse, v[i*8+7]-lse);
            *(float4*)o = a;
            *(float4*)(o + 4) = bq;
        }
    }
}

// ---------------- launch ----------------
extern "C" void kernel_launch(void* const* d_in, const int* in_sizes, int n_in,
                              void* d_out, int out_size, void* d_ws, size_t ws_size,
                              hipStream_t stream)
{
    const float* fc_feats  = (const float*)d_in[0];
    const float* att_feats = (const float*)d_in[1];
    const int*   captions  = (const int*)  d_in[2];
    const float* emb_w     = (const float*)d_in[3];
    const float* fc_w      = (const float*)d_in[4];
    const float* fc_b      = (const float*)d_in[5];
    const float* atte_w    = (const float*)d_in[6];
    const float* atte_b    = (const float*)d_in[7];
    const float* ctx_w     = (const float*)d_in[8];
    const float* ctx_b     = (const float*)d_in[9];
    const float* attl_wih  = (const float*)d_in[10];
    const float* attl_whh  = (const float*)d_in[11];
    const float* attl_bih  = (const float*)d_in[12];
    const float* attl_bhh  = (const float*)d_in[13];
    const float* h2att_w   = (const float*)d_in[14];
    const float* h2att_b   = (const float*)d_in[15];
    const float* alpha_w   = (const float*)d_in[16];
    const float* alpha_b   = (const float*)d_in[17];
    const float* langl_wih = (const float*)d_in[18];
    const float* langl_whh = (const float*)d_in[19];
    const float* langl_bih = (const float*)d_in[20];
    const float* langl_bhh = (const float*)d_in[21];
    const float* cls_w     = (const float*)d_in[22];
    const float* cls_b     = (const float*)d_in[23];

    float* out = (float*)d_out;

    // ---- workspace layout ----
    char* p = (char*)d_ws;
    auto alloc_bf = [&](size_t e) { bf16_t* q = (bf16_t*)p; p += e * 2; return q; };
    auto alloc_f  = [&](size_t e) { float*  q = (float*) p; p += e * 4; return q; };

    // logits [2048][12288] bf16 = 50,331,648 B aliases Wcat_att+Wcat_lang+Win_fc
    bf16_t* Wcat_att    = alloc_bf((size_t)G4 * XH);
    bf16_t* Wcat_lang   = alloc_bf((size_t)G4 * XL3);
    bf16_t* Win_fc      = alloc_bf((size_t)G4 * 1024);
    bf16_t* Win_emb     = alloc_bf((size_t)G4 * 1024);
    bf16_t* fc_wT_b     = alloc_bf((size_t)CFE * CFEAT);
    bf16_t* atte_wT_b   = alloc_bf((size_t)CFE * CFEAT);
    bf16_t* ctx_wT_b    = alloc_bf((size_t)CAH * CFE);
    bf16_t* h2att_wT_b  = alloc_bf((size_t)CAH * CH);
    bf16_t* cls_wT_b    = alloc_bf((size_t)CVP2 * CH);
    bf16_t* fc_feats_b  = alloc_bf((size_t)CB * CFEAT);
    bf16_t* att_feats_b = alloc_bf((size_t)CB * CNREG * CFEAT);  // Gemb aliases this
    bf16_t* att_e_b     = alloc_bf((size_t)CB * CNREG * CFE);
    bf16_t* w_emb       = alloc_bf((size_t)(CT - 1) * CB * 1024);
    bf16_t* fc_e_b      = alloc_bf((size_t)CB * CFE);
    bf16_t* gpre_fc     = alloc_bf((size_t)CB * G4);
    bf16_t* xh0         = alloc_bf((size_t)CB * XH);
    bf16_t* xh1         = alloc_bf((size_t)CB * XH);
    bf16_t* xl3a        = alloc_bf((size_t)CB * XL3);
    bf16_t* xl3b        = alloc_bf((size_t)CB * XL3);
    bf16_t* h_all       = alloc_bf((size_t)CB * (CT - 1) * CH);
    bf16_t* p_att       = alloc_bf((size_t)CB * CNREG * CAH);
    bf16_t* gpart       = alloc_bf((size_t)4 * CB * G4);        // bf16 partials
    float*  cbias_att   = alloc_f (G4);
    float*  cbias_lang  = alloc_f (G4);
    float*  c_att       = alloc_f ((size_t)CB * CH);
    float*  c_lang      = alloc_f ((size_t)CB * CH);

    bf16_t* Gemb   = att_feats_b;         // dead after att_e GEMM
    bf16_t* logits = Wcat_att;            // dead after recurrence loop (exact fit)

    // ---- zero state ----
    hipMemsetAsync(xh0,    0, (size_t)CB * XH * 2, stream);
    hipMemsetAsync(xh1,    0, (size_t)CB * XH * 2, stream);
    hipMemsetAsync(xl3a,   0, (size_t)CB * XL3 * 2, stream);
    hipMemsetAsync(xl3b,   0, (size_t)CB * XL3 * 2, stream);
    hipMemsetAsync(c_att,  0, (size_t)CB * CH * 4, stream);
    hipMemsetAsync(c_lang, 0, (size_t)CB * CH * 4, stream);
    hipMemsetAsync(cls_wT_b + (size_t)CV * CH, 0, (size_t)(CVP2 - CV) * CH * 2, stream);

    const dim3 blk(256);
    auto mk = [](const bf16_t* A, int lda, const bf16_t* W, int ldw, int kt) {
        return Seg{A, W, lda, ldw, kt};
    };

    // ---- one-time weight prep ----
    convert_perm<<<dim3(4, G4), blk, 0, stream>>>(attl_wih, 3048, 0, 1024, Wcat_att, XH, 0, 1024);
    convert_perm<<<dim3(4, G4), blk, 0, stream>>>(attl_whh, 1024, 0, 1024, Wcat_att, XH, 1024, 1024);
    convert_perm<<<dim3(4, G4), blk, 0, stream>>>(attl_wih, 3048, 1024, 1024, Win_fc, 1024, 0, 1024);
    convert_perm<<<dim3(4, G4), blk, 0, stream>>>(attl_wih, 3048, 2048, 1000, Win_emb, 1024, 0, 1024);
    convert_perm<<<dim3(8, G4), blk, 0, stream>>>(langl_wih, 2048, 0, 2048, Wcat_lang, XL3, 0, 2048);
    convert_perm<<<dim3(4, G4), blk, 0, stream>>>(langl_whh, 1024, 0, 1024, Wcat_lang, XL3, 2048, 1024);
    bias_perm<<<16, blk, 0, stream>>>(attl_bih, attl_bhh, cbias_att);
    bias_perm<<<16, blk, 0, stream>>>(langl_bih, langl_bhh, cbias_lang);
    convert_pad<<<dim3(8, CB), blk, 0, stream>>>(fc_feats, fc_feats_b, CFEAT, CFEAT);
    convert_pad<<<dim3(8, CB * CNREG), blk, 0, stream>>>(att_feats, att_feats_b, CFEAT, CFEAT);
    transpose_convert<<<dim3(CFE/32, CFEAT/32), blk, 0, stream>>>(fc_w,    fc_wT_b,    CFEAT, CFE);
    transpose_convert<<<dim3(CFE/32, CFEAT/32), blk, 0, stream>>>(atte_w,  atte_wT_b,  CFEAT, CFE);
    transpose_convert<<<dim3(CAH/32, CFE/32),   blk, 0, stream>>>(ctx_w,   ctx_wT_b,   CFE,   CAH);
    transpose_convert<<<dim3(CAH/32, CH/32),    blk, 0, stream>>>(h2att_w, h2att_wT_b, CH,    CAH);
    transpose_convert<<<dim3(CDIV(CV,32), CH/32), blk, 0, stream>>>(cls_w, cls_wT_b,   CH,    CV);
    emb_all<<<dim3(4, (CT - 1) * CB), blk, 0, stream>>>(emb_w, captions, w_emb);

    // ---- preamble GEMMs ----
    pre_gemm<true,true,2><<<16, blk, 0, stream>>>(
        mk(fc_feats_b, CFEAT, fc_wT_b, CFEAT, 32), 16, fc_b, fc_e_b, CFE);
    pre_gemm<true,true,2><<<576, blk, 0, stream>>>(
        mk(att_feats_b, CFEAT, atte_wT_b, CFEAT, 32), 16, atte_b, att_e_b, CFE);
    pre_gemm<false,true,2><<<288, blk, 0, stream>>>(
        mk(att_e_b, CFE, ctx_wT_b, CFE, 16), 8, ctx_b, p_att, CAH);
    pre_gemm<false,true,1><<<64, blk, 0, stream>>>(
        mk(fc_e_b, CFE, Win_fc, 1024, 16), 1, nullptr, gpre_fc, G4);
    pre_gemm<false,true,3><<<1024, blk, 0, stream>>>(
        mk(w_emb, 1024, Win_emb, 1024, 16), 0, nullptr, Gemb, G4);

    // ---- recurrence: 4 launches per step ----
    for (int t = 0; t < CT - 1; ++t) {
        bf16_t* xh_cur = (t & 1) ? xh1 : xh0;
        bf16_t* xh_nxt = (t & 1) ? xh0 : xh1;
        bf16_t* xl_cur = (t & 1) ? xl3b : xl3a;
        bf16_t* xl_nxt = (t & 1) ? xl3a : xl3b;

        gate_split<0><<<dim3(256, 4), blk, 0, stream>>>(
            xh_cur, XH, Wcat_att, XH, 8, gpart);

        lstm_attn<<<CB, dim3(1024), 0, stream>>>(
            gpart, gpre_fc, Gemb + (size_t)t * CB * G4, cbias_att, c_att,
            p_att, att_e_b, h2att_wT_b, h2att_b, alpha_w, alpha_b,
            xh_nxt, xl_cur);

        gate_split<1><<<dim3(256, 4), blk, 0, stream>>>(
            xl_cur, XL3, Wcat_lang, XL3, 12, gpart);

        lstm_flat<<<512, blk, 0, stream>>>(
            gpart, cbias_lang, c_lang, xh_nxt, xl_nxt, h_all, t);
    }

    // ---- deferred classifier + log-softmax (bf16 logits alias Wcat) ----
    cls_gemm<<<1536, blk, 0, stream>>>(h_all, cls_wT_b, cls_b, logits);
    logsoftmax_bf<<<2048, blk, 0, stream>>>(logits, out);
}

// Round 19
// 1837.494 us; speedup vs baseline: 2.3681x; 1.0381x over previous
//
#include <hip/hip_runtime.h>
#include <cstddef>
#include <cstdint>

// ---------------- problem constants ----------------
constexpr int CV    = 12000;
constexpr int CVP2  = 12288;   // vocab padded to 96 n-tiles of 128
constexpr int CWE   = 1000;
constexpr int CFEAT = 2048;
constexpr int CFE   = 1024;
constexpr int CH    = 1024;
constexpr int CAH   = 512;
constexpr int CNREG = 36;
constexpr int CB    = 128;
constexpr int CT    = 17;
constexpr int G4    = 4096;
constexpr int XH    = 2048;    // xh  = [h_lang | h_att]
constexpr int XL3   = 3072;    // xl3 = [att_res | h_att | h_lang_prev]

#define CDIV(a,b) (((a)+(b)-1)/(b))

typedef __bf16 bf16_t;
typedef __bf16 bf16x8 __attribute__((ext_vector_type(8)));
typedef __bf16 bf16x4 __attribute__((ext_vector_type(4)));
typedef float  f32x4  __attribute__((ext_vector_type(4)));

typedef __attribute__((address_space(3))) uint32_t lds_u32;
typedef const __attribute__((address_space(1))) uint32_t glb_u32;

struct Seg { const bf16_t* A; const bf16_t* W; int lda, ldw, kt; };

// =======================================================================
// pre_gemm: C = A @ W^T + b. BM=128, BN=64, BK=64. (frozen)
// =======================================================================
template<bool RELU, bool OUTBF, int SWZ>
__global__ __launch_bounds__(256)
void pre_gemm(Seg s0, int inner, const float* __restrict__ bias1,
              void* __restrict__ Cout, int ldc)
{
    const int tid = threadIdx.x;
    const int wid = tid >> 6, lane = tid & 63;
    const int wr = wid >> 1, wc = wid & 1;
    const int llo = lane & 15, lhi = lane >> 4;
    const int nb = gridDim.x, id = blockIdx.x;
    const int sw = (id & 7) * (nb >> 3) + (id >> 3);
    int m0, n0;
    if (SWZ == 1)      { n0 = (sw / inner) * 64;  m0 = (sw % inner) * 128; }
    else if (SWZ == 2) { m0 = (sw / inner) * 128; n0 = (sw % inner) * 64;  }
    else {
        const int xcd = id & 7, idx = id >> 3;
        m0 = (((xcd >> 2) << 3) + (idx & 7)) * 128;
        n0 = (((xcd & 3) << 4) + (idx >> 3)) * 64;
    }

    __shared__ __align__(16) uint8_t sm[2][24576];

    const int TT = s0.kt;
    f32x4 acc[4][2] = {};
    uint4 ra[4], rb[2];
    const int srow = tid >> 3, sc = tid & 7;
    const int cswz = (sc ^ (srow & 7)) << 4;

    auto load_tile = [&](int ti) {
        const int k0 = ti << 6;
        #pragma unroll
        for (int i = 0; i < 4; ++i)
            ra[i] = *(const uint4*)(s0.A + (size_t)(m0 + i * 32 + srow) * s0.lda + k0 + sc * 8);
        #pragma unroll
        for (int i = 0; i < 2; ++i)
            rb[i] = *(const uint4*)(s0.W + (size_t)(n0 + i * 32 + srow) * s0.ldw + k0 + sc * 8);
    };
    auto write_tile = [&](int buf) {
        uint8_t* base = sm[buf];
        #pragma unroll
        for (int i = 0; i < 4; ++i) *(uint4*)(base + (i * 32 + srow) * 128 + cswz) = ra[i];
        #pragma unroll
        for (int i = 0; i < 2; ++i) *(uint4*)(base + 16384 + (i * 32 + srow) * 128 + cswz) = rb[i];
    };
    auto compute = [&](int buf) {
        const uint8_t* base = sm[buf];
        const int r7 = llo & 7;
        #pragma unroll
        for (int kk = 0; kk < 2; ++kk) {
            const int coff = ((kk * 4 + lhi) ^ r7) << 4;
            bf16x8 af[4], bg[2];
            #pragma unroll
            for (int fm = 0; fm < 4; ++fm)
                af[fm] = *(const bf16x8*)(base + (wr * 64 + fm * 16 + llo) * 128 + coff);
            #pragma unroll
            for (int fn = 0; fn < 2; ++fn)
                bg[fn] = *(const bf16x8*)(base + 16384 + (wc * 32 + fn * 16 + llo) * 128 + coff);
            #pragma unroll
            for (int fm = 0; fm < 4; ++fm)
                #pragma unroll
                for (int fn = 0; fn < 2; ++fn)
                    acc[fm][fn] = __builtin_amdgcn_mfma_f32_16x16x32_bf16(
                        af[fm], bg[fn], acc[fm][fn], 0, 0, 0);
        }
    };

    load_tile(0); write_tile(0);
    load_tile(1);
    __syncthreads();
    int cur = 0;
    for (int ti = 0; ti < TT; ++ti) {
        if (ti + 1 < TT) write_tile(cur ^ 1);
        if (ti + 2 < TT) load_tile(ti + 2);
        compute(cur);
        __syncthreads();
        cur ^= 1;
    }

    if (OUTBF) {
        bf16_t* st = (bf16_t*)sm[0];
        #pragma unroll
        for (int fn = 0; fn < 2; ++fn) {
            const int lcol = wc * 32 + fn * 16 + llo;
            const float b = bias1 ? bias1[n0 + lcol] : 0.f;
            #pragma unroll
            for (int fm = 0; fm < 4; ++fm)
                #pragma unroll
                for (int r = 0; r < 4; ++r) {
                    float v = acc[fm][fn][r] + b;
                    if (RELU) v = fmaxf(v, 0.f);
                    st[(wr * 64 + fm * 16 + lhi * 4 + r) * 64 + lcol] = (bf16_t)v;
                }
        }
        __syncthreads();
        #pragma unroll
        for (int i = 0; i < 4; ++i) {
            const int q = tid + i * 256;
            const int row = q >> 3, ch = q & 7;
            *(uint4*)((bf16_t*)Cout + (size_t)(m0 + row) * ldc + n0 + ch * 8)
                = *(const uint4*)&st[row * 64 + ch * 8];
        }
    } else {
        const int colb = n0 + wc * 32;
        const int rowb = m0 + wr * 64 + lhi * 4;
        #pragma unroll
        for (int fn = 0; fn < 2; ++fn) {
            const int col = colb + fn * 16 + llo;
            const float b = bias1 ? bias1[col] : 0.f;
            #pragma unroll
            for (int fm = 0; fm < 4; ++fm)
                #pragma unroll
                for (int r = 0; r < 4; ++r) {
                    float v = acc[fm][fn][r] + b;
                    if (RELU) v = fmaxf(v, 0.f);
                    ((float*)Cout)[(size_t)(rowb + fm * 16 + r) * ldc + col] = v;
                }
        }
    }
}

// =======================================================================
// cls_gemm: A[2048,1024] @ W[12288,1024]^T + b -> bf16 logits [2048][CVP2].
// BM=128, BN=128, BK=32, TT=32. Async global_load_lds staging (linear LDS
// dest + pre-swizzled source), 32KB LDS dbuf -> 5 blocks/CU.
// 64B rows, swizzle p = k_chunk ^ ((row>>1)&3) (2-way max aliasing).
// XCD chunking 2m x 4n, m-fast-8. Grid 1536.
// =======================================================================
__global__ __launch_bounds__(256)
void cls_gemm(const bf16_t* __restrict__ A, const bf16_t* __restrict__ W,
              const float* __restrict__ bias, bf16_t* __restrict__ Cout)
{
    const int tid = threadIdx.x;
    const int wid = tid >> 6, lane = tid & 63;
    const int wr = wid >> 1, wc = wid & 1;
    const int llo = lane & 15, lhi = lane >> 4;
    const int id = blockIdx.x;
    const int xcd = id & 7, idx = id >> 3;       // idx 0..191
    const int mg = xcd & 1, ng = xcd >> 1;       // 2m x 4n groups
    const int m0 = (mg * 8 + (idx & 7)) * 128;   // 16 m-tiles
    const int n0 = (ng * 24 + (idx >> 3)) * 128; // 96 n-tiles

    // LDS: per buffer A 128x64B (8KB) + B 128x64B (8KB); dbuf = 32KB total.
    __shared__ __align__(16) uint8_t smA[2][8192];
    __shared__ __align__(16) uint8_t smB[2][8192];

    constexpr int TT = 32;   // K = 1024, BK = 32
    f32x4 acc[4][4] = {};

    // stage: lane l of wave w writes 16B chunks; source k-chunk pre-swizzled.
    //   chunk cq = w*64 + l + i*256; row = cq>>2; physical p = l&3;
    //   source chunk = p ^ ((row>>1)&3) = (l&3) ^ ((l>>3)&3)   (w,i drop out)
    const int scq = (lane & 3) ^ ((lane >> 3) & 3);   // source k-chunk
    auto stage = [&](int buf, int ti) {
        const int k0 = ti << 5;                       // 32 bf16 per tile
        #pragma unroll
        for (int i = 0; i < 2; ++i) {
            const int cq = wid * 64 + lane + i * 256;  // 0..511
            const int row = cq >> 2;
            const bf16_t* ga = A + (size_t)(m0 + row) * CH + k0 + scq * 8;
            __builtin_amdgcn_global_load_lds((glb_u32*)ga,
                (lds_u32*)(smA[buf] + (wid * 64 + i * 256) * 16 + lane * 16), 16, 0, 0);
            const bf16_t* gb = W + (size_t)(n0 + row) * CH + k0 + scq * 8;
            __builtin_amdgcn_global_load_lds((glb_u32*)gb,
                (lds_u32*)(smB[buf] + (wid * 64 + i * 256) * 16 + lane * 16), 16, 0, 0);
        }
    };
    auto compute = [&](int buf) {
        bf16x8 af[4], bg[4];
        #pragma unroll
        for (int fm = 0; fm < 4; ++fm) {
            const int r = wr * 64 + fm * 16 + llo;
            const int p = lhi ^ ((r >> 1) & 3);
            af[fm] = *(const bf16x8*)(smA[buf] + r * 64 + p * 16);
        }
        #pragma unroll
        for (int fn = 0; fn < 4; ++fn) {
            const int r = wc * 64 + fn * 16 + llo;
            const int p = lhi ^ ((r >> 1) & 3);
            bg[fn] = *(const bf16x8*)(smB[buf] + r * 64 + p * 16);
        }
        #pragma unroll
        for (int fm = 0; fm < 4; ++fm)
            #pragma unroll
            for (int fn = 0; fn < 4; ++fn)
                acc[fm][fn] = __builtin_amdgcn_mfma_f32_16x16x32_bf16(
                    af[fm], bg[fn], acc[fm][fn], 0, 0, 0);
    };

    stage(0, 0);
    __syncthreads();
    int cur = 0;
    for (int ti = 0; ti < TT; ++ti) {
        if (ti + 1 < TT) stage(cur ^ 1, ti + 1);
        compute(cur);
        __syncthreads();      // drains async loads + guards buffer reuse
        cur ^= 1;
    }

    // epilogue: stage bf16 [128][128] tile (32KB, reuses smA+smB), full-line stores
    bf16_t* st = (bf16_t*)smA;
    #pragma unroll
    for (int fn = 0; fn < 4; ++fn) {
        const int lcol = wc * 64 + fn * 16 + llo;
        const int col = n0 + lcol;
        const float b = (col < CV) ? bias[col] : 0.f;
        #pragma unroll
        for (int fm = 0; fm < 4; ++fm)
            #pragma unroll
            for (int r = 0; r < 4; ++r)
                st[(wr * 64 + fm * 16 + lhi * 4 + r) * 128 + lcol]
                    = (bf16_t)(acc[fm][fn][r] + b);
    }
    __syncthreads();
    #pragma unroll
    for (int i = 0; i < 8; ++i) {
        const int q = tid + i * 256;
        const int row = q >> 4, ch = q & 15;
        *(uint4*)(Cout + (size_t)(m0 + row) * CVP2 + n0 + ch * 8)
            = *(const uint4*)&st[row * 128 + ch * 8];
    }
}

// =======================================================================
// gate_split: split-K gate GEMM partials (bf16). (frozen from R18)
// =======================================================================
template<int TAG>
__global__ __launch_bounds__(256)
void gate_split(const bf16_t* __restrict__ A, int lda,
                const bf16_t* __restrict__ W, int ldw, int ktz,
                bf16_t* __restrict__ gpart)
{
    const int tid = threadIdx.x;
    const int w = tid >> 6, lane = tid & 63;
    const int llo = lane & 15, lhi = lane >> 4;
    const int n0 = blockIdx.x * 16;
    const int z  = blockIdx.y;
    const int kb = z * ktz;

    __shared__ __align__(16) uint8_t smA[2][16384];   // 128 rows x 128B
    __shared__ __align__(16) uint8_t smB[2][2048];    // 16 rows x 128B

    f32x4 acc0 = {0.f,0.f,0.f,0.f}, acc1 = {0.f,0.f,0.f,0.f};

    const int arow = tid >> 3, ac = tid & 7;
    const int asc = ac ^ (arow & 7);
    const int wvoff = (tid >> 6) * 1024;

    auto stage = [&](int buf, int ti) {
        const int k0 = (kb + ti) << 6;
        #pragma unroll
        for (int i = 0; i < 4; ++i) {
            const bf16_t* gp = A + (size_t)(arow + i * 32) * lda + k0 + asc * 8;
            __builtin_amdgcn_global_load_lds((glb_u32*)gp,
                (lds_u32*)(smA[buf] + i * 4096 + wvoff), 16, 0, 0);
        }
        if (tid < 128) {
            const int brow = tid >> 3, bc = tid & 7;
            const int bsc = bc ^ (brow & 7);
            const bf16_t* gp = W + (size_t)(n0 + brow) * ldw + k0 + bsc * 8;
            __builtin_amdgcn_global_load_lds((glb_u32*)gp,
                (lds_u32*)(smB[buf] + wvoff), 16, 0, 0);
        }
    };
    auto compute = [&](int buf) {
        const int r7 = llo & 7;
        #pragma unroll
        for (int kk = 0; kk < 2; ++kk) {
            const int coff = ((kk * 4 + lhi) ^ r7) << 4;
            bf16x8 a0 = *(const bf16x8*)(smA[buf] + (w * 32 + llo) * 128 + coff);
            bf16x8 a1 = *(const bf16x8*)(smA[buf] + (w * 32 + 16 + llo) * 128 + coff);
            bf16x8 bb = *(const bf16x8*)(smB[buf] + llo * 128 + coff);
            acc0 = __builtin_amdgcn_mfma_f32_16x16x32_bf16(a0, bb, acc0, 0, 0, 0);
            acc1 = __builtin_amdgcn_mfma_f32_16x16x32_bf16(a1, bb, acc1, 0, 0, 0);
        }
    };

    stage(0, 0);
    __syncthreads();
    int cur = 0;
    for (int ti = 0; ti < ktz; ++ti) {
        if (ti + 1 < ktz) stage(cur ^ 1, ti + 1);
        compute(cur);
        __syncthreads();
        cur ^= 1;
    }

    bf16_t* gp = gpart + (size_t)z * CB * G4;
    const int col = n0 + llo;
    #pragma unroll
    for (int r = 0; r < 4; ++r) {
        gp[(size_t)(w * 32 + lhi * 4 + r) * G4 + col] = (bf16_t)acc0[r];
        gp[(size_t)(w * 32 + 16 + lhi * 4 + r) * G4 + col] = (bf16_t)acc1[r];
    }
}

// =======================================================================
// lstm_attn: 1024 threads. (frozen from R18)
// =======================================================================
__global__ __launch_bounds__(1024)
void lstm_attn(const bf16_t* __restrict__ gpart, const bf16_t* __restrict__ gpre_fc,
               const bf16_t* __restrict__ gemb,
               const float* __restrict__ cbias, float* __restrict__ c_att,
               const bf16_t* __restrict__ p_att, const bf16_t* __restrict__ att_e,
               const bf16_t* __restrict__ h2att_wT, const float* __restrict__ h2att_b,
               const float* __restrict__ alpha_w, const float* __restrict__ alpha_b,
               bf16_t* __restrict__ xh_nxt, bf16_t* __restrict__ xl_cur)
{
    __shared__ float sh[CH];
    __shared__ float shq[CAH];
    __shared__ float se[64], salpha[64];
    const int b = blockIdx.x, tid = threadIdx.x;   // 0..1023

    {
        const int j = tid;
        float g0 = 0.f, g1 = 0.f, g2 = 0.f, g3 = 0.f;
        #pragma unroll
        for (int z = 0; z < 4; ++z) {
            bf16x4 g = *(const bf16x4*)(gpart + (size_t)z * CB * G4 + (size_t)b * G4 + 4 * j);
            g0 += (float)g[0]; g1 += (float)g[1]; g2 += (float)g[2]; g3 += (float)g[3];
        }
        f32x4 cb = *(const f32x4*)(cbias + 4 * j);
        bf16x4 gf4 = *(const bf16x4*)(gpre_fc + (size_t)b * G4 + 4 * j);
        bf16x4 ge4 = *(const bf16x4*)(gemb + (size_t)b * G4 + 4 * j);
        const float gi = g0 + cb[0] + (float)gf4[0] + (float)ge4[0];
        const float gf = g1 + cb[1] + (float)gf4[1] + (float)ge4[1];
        const float gg = g2 + cb[2] + (float)gf4[2] + (float)ge4[2];
        const float go = g3 + cb[3] + (float)gf4[3] + (float)ge4[3];
        const float si = 1.f / (1.f + expf(-gi));
        const float sf = 1.f / (1.f + expf(-gf));
        const float so = 1.f / (1.f + expf(-go));
        const float cn = sf * c_att[b * CH + j] + si * tanhf(gg);
        const float hn = so * tanhf(cn);
        c_att[b * CH + j] = cn;
        sh[j] = hn;
        const bf16_t hb = (bf16_t)hn;
        xh_nxt[(size_t)b * XH + 1024 + j] = hb;
        xl_cur[(size_t)b * XL3 + 1024 + j] = hb;
    }
    __syncthreads();

    {
        const int q2 = tid & 1, n = tid >> 1;
        const bf16_t* wrow = h2att_wT + (size_t)n * CH + q2 * 512;
        float s = 0.f;
        #pragma unroll 4
        for (int k = 0; k < 512; k += 8) {
            bf16x8 w8 = *(const bf16x8*)(wrow + k);
            #pragma unroll
            for (int j = 0; j < 8; ++j) s = fmaf((float)w8[j], sh[q2 * 512 + k + j], s);
        }
        s += __shfl_xor(s, 1);
        if (q2 == 0) shq[n] = s + h2att_b[n];
    }
    __syncthreads();

    {
        const int wave = tid >> 6, lane = tid & 63;
        for (int n = wave; n < CNREG; n += 16) {
            const bf16_t* pr = p_att + ((size_t)b * CNREG + n) * CAH;
            float s = 0.f;
            #pragma unroll
            for (int q = 0; q < CAH / 64; ++q) {
                const int d = lane + q * 64;
                s += alpha_w[d] * tanhf((float)pr[d] + shq[d]);
            }
            for (int off = 32; off; off >>= 1) s += __shfl_down(s, off);
            if (lane == 0) se[n] = s + alpha_b[0];
        }
    }
    __syncthreads();

    {
        float mx = -1e30f;
        for (int n = 0; n < CNREG; ++n) mx = fmaxf(mx, se[n]);
        float sum = 0.f;
        for (int n = 0; n < CNREG; ++n) sum += expf(se[n] - mx);
        if (tid < CNREG) salpha[tid] = expf(se[tid] - mx) / sum;
    }
    __syncthreads();

    {
        const int d = tid;
        float s = 0.f;
        const bf16_t* ae = att_e + (size_t)b * CNREG * CFE + d;
        #pragma unroll 4
        for (int n = 0; n < CNREG; ++n)
            s = fmaf(salpha[n], (float)ae[(size_t)n * CFE], s);
        xl_cur[(size_t)b * XL3 + d] = (bf16_t)s;
    }
}

// ---- lstm_flat (frozen from R18) ----
__global__ __launch_bounds__(256)
void lstm_flat(const bf16_t* __restrict__ gpart, const float* __restrict__ cbias,
               float* __restrict__ c,
               bf16_t* __restrict__ xh_nxt, bf16_t* __restrict__ xl_nxt,
               bf16_t* __restrict__ h_all, int t)
{
    const int idx = blockIdx.x * 256 + threadIdx.x;
    const int b = idx >> 10, j = idx & 1023;
    float g0 = 0.f, g1 = 0.f, g2 = 0.f, g3 = 0.f;
    #pragma unroll
    for (int z = 0; z < 4; ++z) {
        bf16x4 g = *(const bf16x4*)(gpart + (size_t)z * CB * G4 + (size_t)b * G4 + 4 * j);
        g0 += (float)g[0]; g1 += (float)g[1]; g2 += (float)g[2]; g3 += (float)g[3];
    }
    f32x4 cb = *(const f32x4*)(cbias + 4 * j);
    const float si = 1.f / (1.f + expf(-(g0 + cb[0])));
    const float sf = 1.f / (1.f + expf(-(g1 + cb[1])));
    const float so = 1.f / (1.f + expf(-(g3 + cb[3])));
    const float cn = sf * c[idx] + si * tanhf(g2 + cb[2]);
    const float hn = so * tanhf(cn);
    c[idx] = cn;
    const bf16_t hb = (bf16_t)hn;
    xh_nxt[(size_t)b * XH + j] = hb;
    xl_nxt[(size_t)b * XL3 + 2048 + j] = hb;
    h_all[((size_t)b * (CT - 1) + t) * CH + j] = hb;
}

// ---------------- prep kernels (frozen) ----------------
__global__ void convert_pad(const float* __restrict__ src, bf16_t* __restrict__ dst,
                            int C, int Cp)
{
    const int r = blockIdx.y;
    const int c = blockIdx.x * 256 + threadIdx.x;
    if (c >= Cp) return;
    dst[(size_t)r * Cp + c] = (c < C) ? (bf16_t)src[(size_t)r * C + c] : (bf16_t)0.f;
}

__global__ void convert_perm(const float* __restrict__ src, int srcld, int scol0,
                             int valid, bf16_t* __restrict__ dst, int dstld, int dcol0,
                             int ncols)
{
    const int rp = blockIdx.y;
    const int c = blockIdx.x * 256 + threadIdx.x;
    if (c >= ncols) return;
    const int rs = (rp & 3) * 1024 + (rp >> 2);
    const float v = (c < valid) ? src[(size_t)rs * srcld + scol0 + c] : 0.f;
    dst[(size_t)rp * dstld + dcol0 + c] = (bf16_t)v;
}

__global__ void bias_perm(const float* __restrict__ bih, const float* __restrict__ bhh,
                          float* __restrict__ dst)
{
    const int rp = blockIdx.x * 256 + threadIdx.x;
    if (rp >= G4) return;
    const int rs = (rp & 3) * 1024 + (rp >> 2);
    dst[rp] = bih[rs] + bhh[rs];
}

__global__ __launch_bounds__(256)
void transpose_convert(const float* __restrict__ src, bf16_t* __restrict__ dst,
                       int K, int N)
{
    __shared__ float tile[32][33];
    const int n0 = blockIdx.x * 32, k0 = blockIdx.y * 32;
    const int tx = threadIdx.x & 31, ty = threadIdx.x >> 5;
    #pragma unroll
    for (int i = 0; i < 4; ++i) {
        const int k = k0 + ty + i * 8, n = n0 + tx;
        tile[ty + i * 8][tx] = (k < K && n < N) ? src[(size_t)k * N + n] : 0.f;
    }
    __syncthreads();
    #pragma unroll
    for (int i = 0; i < 4; ++i) {
        const int n = n0 + ty + i * 8, k = k0 + tx;
        if (n < N && k < K) dst[(size_t)n * K + k] = (bf16_t)tile[tx][ty + i * 8];
    }
}

__global__ void emb_all(const float* __restrict__ emb_w,
                        const int* __restrict__ captions, bf16_t* __restrict__ w_emb)
{
    const int r = blockIdx.y;
    const int j = blockIdx.x * 256 + threadIdx.x;
    const int t = r >> 7, b = r & 127;
    const int tok = captions[b * CT + t];
    const float v = (j < CWE) ? fmaxf(emb_w[(size_t)tok * CWE + j], 0.f) : 0.f;
    w_emb[(size_t)r * 1024 + j] = (bf16_t)v;
}

// ---- log-softmax from bf16 logits [2048][CVP2] -> fp32 out [2048][CV] ----
__global__ __launch_bounds__(256)
void logsoftmax_bf(const bf16_t* __restrict__ lg, float* __restrict__ out)
{
    __shared__ float red[4];
    const int r = blockIdx.x, tid = threadIdx.x;
    const bf16_t* row = lg + (size_t)r * CVP2;

    float v[48];
    float mx = -1e30f;
    #pragma unroll
    for (int i = 0; i < 6; ++i) {
        const int c = tid + i * 256;
        if (c < 1500) {
            bf16x8 x = *(const bf16x8*)(row + c * 8);
            #pragma unroll
            for (int j = 0; j < 8; ++j) {
                v[i * 8 + j] = (float)x[j];
                mx = fmaxf(mx, v[i * 8 + j]);
            }
        } else {
            #pragma unroll
            for (int j = 0; j < 8; ++j) v[i * 8 + j] = -1e30f;
        }
    }
    for (int off = 32; off; off >>= 1) mx = fmaxf(mx, __shfl_down(mx, off));
    if ((tid & 63) == 0) red[tid >> 6] = mx;
    __syncthreads();
    mx = fmaxf(fmaxf(red[0], red[1]), fmaxf(red[2], red[3]));
    __syncthreads();

    float sum = 0.f;
    #pragma unroll
    for (int i = 0; i < 6; ++i)
        if (tid + i * 256 < 1500)
            #pragma unroll
            for (int j = 0; j < 8; ++j) sum += expf(v[i * 8 + j] - mx);
    for (int off = 32; off; off >>= 1) sum += __shfl_down(sum, off);
    if ((tid & 63) == 0) red[tid >> 6] = sum;
    __syncthreads();
    sum = red[0] + red[1] + red[2] + red[3];
    const float lse = mx + logf(sum);

    #pragma unroll
    for (int i = 0; i < 6; ++i) {
        const int c = tid + i * 256;
        if (c < 1500) {
            float* o = out + (size_t)r * CV + c * 8;
            float4 a = make_float4(v[i*8+0]-lse, v[i*8+1]-lse, v[i*8+2]-lse, v[i*8+3]-lse);
            float4 bq = make_float4(v[i*8+4]-lse, v[i*8+5]-lse, v[i*8+6]-lse, v[i*8+7]-lse);
            *(float4*)o = a;
            *(float4*)(o + 4) = bq;
        }
    }
}

// ---------------- launch ----------------
extern "C" void kernel_launch(void* const* d_in, const int* in_sizes, int n_in,
                              void* d_out, int out_size, void* d_ws, size_t ws_size,
                              hipStream_t stream)
{
    const float* fc_feats  = (const float*)d_in[0];
    const float* att_feats = (const float*)d_in[1];
    const int*   captions  = (const int*)  d_in[2];
    const float* emb_w     = (const float*)d_in[3];
    const float* fc_w      = (const float*)d_in[4];
    const float* fc_b      = (const float*)d_in[5];
    const float* atte_w    = (const float*)d_in[6];
    const float* atte_b    = (const float*)d_in[7];
    const float* ctx_w     = (const float*)d_in[8];
    const float* ctx_b     = (const float*)d_in[9];
    const float* attl_wih  = (const float*)d_in[10];
    const float* attl_whh  = (const float*)d_in[11];
    const float* attl_bih  = (const float*)d_in[12];
    const float* attl_bhh  = (const float*)d_in[13];
    const float* h2att_w   = (const float*)d_in[14];
    const float* h2att_b   = (const float*)d_in[15];
    const float* alpha_w   = (const float*)d_in[16];
    const float* alpha_b   = (const float*)d_in[17];
    const float* langl_wih = (const float*)d_in[18];
    const float* langl_whh = (const float*)d_in[19];
    const float* langl_bih = (const float*)d_in[20];
    const float* langl_bhh = (const float*)d_in[21];
    const float* cls_w     = (const float*)d_in[22];
    const float* cls_b     = (const float*)d_in[23];

    float* out = (float*)d_out;

    // ---- workspace layout ----
    char* p = (char*)d_ws;
    auto alloc_bf = [&](size_t e) { bf16_t* q = (bf16_t*)p; p += e * 2; return q; };
    auto alloc_f  = [&](size_t e) { float*  q = (float*) p; p += e * 4; return q; };

    bf16_t* Wcat_att    = alloc_bf((size_t)G4 * XH);
    bf16_t* Wcat_lang   = alloc_bf((size_t)G4 * XL3);
    bf16_t* Win_fc      = alloc_bf((size_t)G4 * 1024);
    bf16_t* Win_emb     = alloc_bf((size_t)G4 * 1024);
    bf16_t* fc_wT_b     = alloc_bf((size_t)CFE * CFEAT);
    bf16_t* atte_wT_b   = alloc_bf((size_t)CFE * CFEAT);
    bf16_t* ctx_wT_b    = alloc_bf((size_t)CAH * CFE);
    bf16_t* h2att_wT_b  = alloc_bf((size_t)CAH * CH);
    bf16_t* cls_wT_b    = alloc_bf((size_t)CVP2 * CH);
    bf16_t* fc_feats_b  = alloc_bf((size_t)CB * CFEAT);
    bf16_t* att_feats_b = alloc_bf((size_t)CB * CNREG * CFEAT);  // Gemb aliases this
    bf16_t* att_e_b     = alloc_bf((size_t)CB * CNREG * CFE);
    bf16_t* w_emb       = alloc_bf((size_t)(CT - 1) * CB * 1024);
    bf16_t* fc_e_b      = alloc_bf((size_t)CB * CFE);
    bf16_t* gpre_fc     = alloc_bf((size_t)CB * G4);
    bf16_t* xh0         = alloc_bf((size_t)CB * XH);
    bf16_t* xh1         = alloc_bf((size_t)CB * XH);
    bf16_t* xl3a        = alloc_bf((size_t)CB * XL3);
    bf16_t* xl3b        = alloc_bf((size_t)CB * XL3);
    bf16_t* h_all       = alloc_bf((size_t)CB * (CT - 1) * CH);
    bf16_t* p_att       = alloc_bf((size_t)CB * CNREG * CAH);
    bf16_t* gpart       = alloc_bf((size_t)4 * CB * G4);
    float*  cbias_att   = alloc_f (G4);
    float*  cbias_lang  = alloc_f (G4);
    float*  c_att       = alloc_f ((size_t)CB * CH);
    float*  c_lang      = alloc_f ((size_t)CB * CH);

    bf16_t* Gemb   = att_feats_b;         // dead after att_e GEMM
    bf16_t* logits = Wcat_att;            // dead after recurrence loop (exact fit)

    // ---- zero state ----
    hipMemsetAsync(xh0,    0, (size_t)CB * XH * 2, stream);
    hipMemsetAsync(xh1,    0, (size_t)CB * XH * 2, stream);
    hipMemsetAsync(xl3a,   0, (size_t)CB * XL3 * 2, stream);
    hipMemsetAsync(xl3b,   0, (size_t)CB * XL3 * 2, stream);
    hipMemsetAsync(c_att,  0, (size_t)CB * CH * 4, stream);
    hipMemsetAsync(c_lang, 0, (size_t)CB * CH * 4, stream);
    hipMemsetAsync(cls_wT_b + (size_t)CV * CH, 0, (size_t)(CVP2 - CV) * CH * 2, stream);

    const dim3 blk(256);
    auto mk = [](const bf16_t* A, int lda, const bf16_t* W, int ldw, int kt) {
        return Seg{A, W, lda, ldw, kt};
    };

    // ---- one-time weight prep ----
    convert_perm<<<dim3(4, G4), blk, 0, stream>>>(attl_wih, 3048, 0, 1024, Wcat_att, XH, 0, 1024);
    convert_perm<<<dim3(4, G4), blk, 0, stream>>>(attl_whh, 1024, 0, 1024, Wcat_att, XH, 1024, 1024);
    convert_perm<<<dim3(4, G4), blk, 0, stream>>>(attl_wih, 3048, 1024, 1024, Win_fc, 1024, 0, 1024);
    convert_perm<<<dim3(4, G4), blk, 0, stream>>>(attl_wih, 3048, 2048, 1000, Win_emb, 1024, 0, 1024);
    convert_perm<<<dim3(8, G4), blk, 0, stream>>>(langl_wih, 2048, 0, 2048, Wcat_lang, XL3, 0, 2048);
    convert_perm<<<dim3(4, G4), blk, 0, stream>>>(langl_whh, 1024, 0, 1024, Wcat_lang, XL3, 2048, 1024);
    bias_perm<<<16, blk, 0, stream>>>(attl_bih, attl_bhh, cbias_att);
    bias_perm<<<16, blk, 0, stream>>>(langl_bih, langl_bhh, cbias_lang);
    convert_pad<<<dim3(8, CB), blk, 0, stream>>>(fc_feats, fc_feats_b, CFEAT, CFEAT);
    convert_pad<<<dim3(8, CB * CNREG), blk, 0, stream>>>(att_feats, att_feats_b, CFEAT, CFEAT);
    transpose_convert<<<dim3(CFE/32, CFEAT/32), blk, 0, stream>>>(fc_w,    fc_wT_b,    CFEAT, CFE);
    transpose_convert<<<dim3(CFE/32, CFEAT/32), blk, 0, stream>>>(atte_w,  atte_wT_b,  CFEAT, CFE);
    transpose_convert<<<dim3(CAH/32, CFE/32),   blk, 0, stream>>>(ctx_w,   ctx_wT_b,   CFE,   CAH);
    transpose_convert<<<dim3(CAH/32, CH/32),    blk, 0, stream>>>(h2att_w, h2att_wT_b, CH,    CAH);
    transpose_convert<<<dim3(CDIV(CV,32), CH/32), blk, 0, stream>>>(cls_w, cls_wT_b,   CH,    CV);
    emb_all<<<dim3(4, (CT - 1) * CB), blk, 0, stream>>>(emb_w, captions, w_emb);

    // ---- preamble GEMMs ----
    pre_gemm<true,true,2><<<16, blk, 0, stream>>>(
        mk(fc_feats_b, CFEAT, fc_wT_b, CFEAT, 32), 16, fc_b, fc_e_b, CFE);
    pre_gemm<true,true,2><<<576, blk, 0, stream>>>(
        mk(att_feats_b, CFEAT, atte_wT_b, CFEAT, 32), 16, atte_b, att_e_b, CFE);
    pre_gemm<false,true,2><<<288, blk, 0, stream>>>(
        mk(att_e_b, CFE, ctx_wT_b, CFE, 16), 8, ctx_b, p_att, CAH);
    pre_gemm<false,true,1><<<64, blk, 0, stream>>>(
        mk(fc_e_b, CFE, Win_fc, 1024, 16), 1, nullptr, gpre_fc, G4);
    pre_gemm<false,true,3><<<1024, blk, 0, stream>>>(
        mk(w_emb, 1024, Win_emb, 1024, 16), 0, nullptr, Gemb, G4);

    // ---- recurrence: 4 launches per step ----
    for (int t = 0; t < CT - 1; ++t) {
        bf16_t* xh_cur = (t & 1) ? xh1 : xh0;
        bf16_t* xh_nxt = (t & 1) ? xh0 : xh1;
        bf16_t* xl_cur = (t & 1) ? xl3b : xl3a;
        bf16_t* xl_nxt = (t & 1) ? xl3a : xl3b;

        gate_split<0><<<dim3(256, 4), blk, 0, stream>>>(
            xh_cur, XH, Wcat_att, XH, 8, gpart);

        lstm_attn<<<CB, dim3(1024), 0, stream>>>(
            gpart, gpre_fc, Gemb + (size_t)t * CB * G4, cbias_att, c_att,
            p_att, att_e_b, h2att_wT_b, h2att_b, alpha_w, alpha_b,
            xh_nxt, xl_cur);

        gate_split<1><<<dim3(256, 4), blk, 0, stream>>>(
            xl_cur, XL3, Wcat_lang, XL3, 12, gpart);

        lstm_flat<<<512, blk, 0, stream>>>(
            gpart, cbias_lang, c_lang, xh_nxt, xl_nxt, h_all, t);
    }

    // ---- deferred classifier + log-softmax ----
    cls_gemm<<<1536, blk, 0, stream>>>(h_all, cls_wT_b, cls_b, logits);
    logsoftmax_bf<<<2048, blk, 0, stream>>>(logits, out);
}

// Round 20
// 1573.814 us; speedup vs baseline: 2.7648x; 1.1675x over previous
//
#include <hip/hip_runtime.h>
#include <cstddef>
#include <cstdint>

// ---------------- problem constants ----------------
constexpr int CV    = 12000;
constexpr int CVP2  = 12288;   // vocab padded to 96 n-tiles of 128
constexpr int CWE   = 1000;
constexpr int CFEAT = 2048;
constexpr int CFE   = 1024;
constexpr int CH    = 1024;
constexpr int CAH   = 512;
constexpr int CNREG = 36;
constexpr int CB    = 128;
constexpr int CT    = 17;
constexpr int G4    = 4096;
constexpr int XH    = 2048;    // xh  = [h_lang | h_att]
constexpr int XL3   = 3072;    // xl3 = [att_res | h_att | h_lang_prev]

#define CDIV(a,b) (((a)+(b)-1)/(b))

typedef __bf16 bf16_t;
typedef __bf16 bf16x8 __attribute__((ext_vector_type(8)));
typedef __bf16 bf16x4 __attribute__((ext_vector_type(4)));
typedef float  f32x4  __attribute__((ext_vector_type(4)));

typedef __attribute__((address_space(3))) uint32_t lds_u32;
typedef const __attribute__((address_space(1))) uint32_t glb_u32;

struct Seg { const bf16_t* A; const bf16_t* W; int lda, ldw, kt; };  // kt in BK=32 units

// =======================================================================
// pre_gemm: C = A @ W^T + b. BM=128, BN=64, BK=32. Async global_load_lds
// staging (linear LDS dest + pre-swizzled source, proven in cls_gemm).
// 24KB LDS dbuf -> 6 blocks/CU. 64B rows, swizzle p = kc ^ ((row>>1)&3).
// SWZ=1 n-slow, SWZ=2 m-slow, SWZ=3 2D chunks (2m x 4n; 16m x 64n grid).
// =======================================================================
template<bool RELU, bool OUTBF, int SWZ>
__global__ __launch_bounds__(256)
void pre_gemm(Seg s0, int inner, const float* __restrict__ bias1,
              void* __restrict__ Cout, int ldc)
{
    const int tid = threadIdx.x;
    const int wid = tid >> 6, lane = tid & 63;
    const int wr = wid >> 1, wc = wid & 1;
    const int llo = lane & 15, lhi = lane >> 4;
    const int nb = gridDim.x, id = blockIdx.x;
    const int sw = (id & 7) * (nb >> 3) + (id >> 3);
    int m0, n0;
    if (SWZ == 1)      { n0 = (sw / inner) * 64;  m0 = (sw % inner) * 128; }
    else if (SWZ == 2) { m0 = (sw / inner) * 128; n0 = (sw % inner) * 64;  }
    else {
        const int xcd = id & 7, idx = id >> 3;
        m0 = (((xcd >> 2) << 3) + (idx & 7)) * 128;
        n0 = (((xcd & 3) << 4) + (idx >> 3)) * 64;
    }

    __shared__ __align__(16) uint8_t smA[2][8192];   // 128 rows x 64B
    __shared__ __align__(16) uint8_t smB[2][4096];   // 64 rows x 64B

    const int TT = s0.kt;
    f32x4 acc[4][2] = {};

    const int scq = (lane & 3) ^ ((lane >> 3) & 3);   // pre-swizzled source k-chunk
    auto stage = [&](int buf, int ti) {
        const int k0 = ti << 5;   // BK = 32 bf16
        #pragma unroll
        for (int i = 0; i < 2; ++i) {              // A: 512 chunks, 2/thread
            const int cq = wid * 64 + lane + i * 256;
            const int row = cq >> 2;
            const bf16_t* ga = s0.A + (size_t)(m0 + row) * s0.lda + k0 + scq * 8;
            __builtin_amdgcn_global_load_lds((glb_u32*)ga,
                (lds_u32*)(smA[buf] + (wid * 64 + i * 256) * 16 + lane * 16), 16, 0, 0);
        }
        {                                           // B: 256 chunks, 1/thread
            const int row = tid >> 2;
            const bf16_t* gb = s0.W + (size_t)(n0 + row) * s0.ldw + k0 + scq * 8;
            __builtin_amdgcn_global_load_lds((glb_u32*)gb,
                (lds_u32*)(smB[buf] + wid * 1024 + lane * 16), 16, 0, 0);
        }
    };
    auto compute = [&](int buf) {
        bf16x8 af[4], bg[2];
        #pragma unroll
        for (int fm = 0; fm < 4; ++fm) {
            const int r = wr * 64 + fm * 16 + llo;
            const int p = lhi ^ ((r >> 1) & 3);
            af[fm] = *(const bf16x8*)(smA[buf] + r * 64 + p * 16);
        }
        #pragma unroll
        for (int fn = 0; fn < 2; ++fn) {
            const int r = wc * 32 + fn * 16 + llo;
            const int p = lhi ^ ((r >> 1) & 3);
            bg[fn] = *(const bf16x8*)(smB[buf] + r * 64 + p * 16);
        }
        #pragma unroll
        for (int fm = 0; fm < 4; ++fm)
            #pragma unroll
            for (int fn = 0; fn < 2; ++fn)
                acc[fm][fn] = __builtin_amdgcn_mfma_f32_16x16x32_bf16(
                    af[fm], bg[fn], acc[fm][fn], 0, 0, 0);
    };

    stage(0, 0);
    __syncthreads();
    int cur = 0;
    for (int ti = 0; ti < TT; ++ti) {
        if (ti + 1 < TT) stage(cur ^ 1, ti + 1);
        compute(cur);
        __syncthreads();
        cur ^= 1;
    }

    if (OUTBF) {
        bf16_t* st = (bf16_t*)smA;   // [128][64] bf16 = 16KB
        #pragma unroll
        for (int fn = 0; fn < 2; ++fn) {
            const int lcol = wc * 32 + fn * 16 + llo;
            const float b = bias1 ? bias1[n0 + lcol] : 0.f;
            #pragma unroll
            for (int fm = 0; fm < 4; ++fm)
                #pragma unroll
                for (int r = 0; r < 4; ++r) {
                    float v = acc[fm][fn][r] + b;
                    if (RELU) v = fmaxf(v, 0.f);
                    st[(wr * 64 + fm * 16 + lhi * 4 + r) * 64 + lcol] = (bf16_t)v;
                }
        }
        __syncthreads();
        #pragma unroll
        for (int i = 0; i < 4; ++i) {
            const int q = tid + i * 256;
            const int row = q >> 3, ch = q & 7;
            *(uint4*)((bf16_t*)Cout + (size_t)(m0 + row) * ldc + n0 + ch * 8)
                = *(const uint4*)&st[row * 64 + ch * 8];
        }
    } else {
        const int colb = n0 + wc * 32;
        const int rowb = m0 + wr * 64 + lhi * 4;
        #pragma unroll
        for (int fn = 0; fn < 2; ++fn) {
            const int col = colb + fn * 16 + llo;
            const float b = bias1 ? bias1[col] : 0.f;
            #pragma unroll
            for (int fm = 0; fm < 4; ++fm)
                #pragma unroll
                for (int r = 0; r < 4; ++r) {
                    float v = acc[fm][fn][r] + b;
                    if (RELU) v = fmaxf(v, 0.f);
                    ((float*)Cout)[(size_t)(rowb + fm * 16 + r) * ldc + col] = v;
                }
        }
    }
}

// =======================================================================
// cls_gemm: A[2048,1024] @ W[12288,1024]^T + b -> bf16 logits [2048][CVP2].
// BM=128, BN=128, BK=32, TT=32. (frozen from R19 — proven)
// =======================================================================
__global__ __launch_bounds__(256)
void cls_gemm(const bf16_t* __restrict__ A, const bf16_t* __restrict__ W,
              const float* __restrict__ bias, bf16_t* __restrict__ Cout)
{
    const int tid = threadIdx.x;
    const int wid = tid >> 6, lane = tid & 63;
    const int wr = wid >> 1, wc = wid & 1;
    const int llo = lane & 15, lhi = lane >> 4;
    const int id = blockIdx.x;
    const int xcd = id & 7, idx = id >> 3;
    const int mg = xcd & 1, ng = xcd >> 1;
    const int m0 = (mg * 8 + (idx & 7)) * 128;
    const int n0 = (ng * 24 + (idx >> 3)) * 128;

    __shared__ __align__(16) uint8_t smA[2][8192];
    __shared__ __align__(16) uint8_t smB[2][8192];

    constexpr int TT = 32;
    f32x4 acc[4][4] = {};

    const int scq = (lane & 3) ^ ((lane >> 3) & 3);
    auto stage = [&](int buf, int ti) {
        const int k0 = ti << 5;
        #pragma unroll
        for (int i = 0; i < 2; ++i) {
            const int cq = wid * 64 + lane + i * 256;
            const int row = cq >> 2;
            const bf16_t* ga = A + (size_t)(m0 + row) * CH + k0 + scq * 8;
            __builtin_amdgcn_global_load_lds((glb_u32*)ga,
                (lds_u32*)(smA[buf] + (wid * 64 + i * 256) * 16 + lane * 16), 16, 0, 0);
            const bf16_t* gb = W + (size_t)(n0 + row) * CH + k0 + scq * 8;
            __builtin_amdgcn_global_load_lds((glb_u32*)gb,
                (lds_u32*)(smB[buf] + (wid * 64 + i * 256) * 16 + lane * 16), 16, 0, 0);
        }
    };
    auto compute = [&](int buf) {
        bf16x8 af[4], bg[4];
        #pragma unroll
        for (int fm = 0; fm < 4; ++fm) {
            const int r = wr * 64 + fm * 16 + llo;
            const int p = lhi ^ ((r >> 1) & 3);
            af[fm] = *(const bf16x8*)(smA[buf] + r * 64 + p * 16);
        }
        #pragma unroll
        for (int fn = 0; fn < 4; ++fn) {
            const int r = wc * 64 + fn * 16 + llo;
            const int p = lhi ^ ((r >> 1) & 3);
            bg[fn] = *(const bf16x8*)(smB[buf] + r * 64 + p * 16);
        }
        #pragma unroll
        for (int fm = 0; fm < 4; ++fm)
            #pragma unroll
            for (int fn = 0; fn < 4; ++fn)
                acc[fm][fn] = __builtin_amdgcn_mfma_f32_16x16x32_bf16(
                    af[fm], bg[fn], acc[fm][fn], 0, 0, 0);
    };

    stage(0, 0);
    __syncthreads();
    int cur = 0;
    for (int ti = 0; ti < TT; ++ti) {
        if (ti + 1 < TT) stage(cur ^ 1, ti + 1);
        compute(cur);
        __syncthreads();
        cur ^= 1;
    }

    bf16_t* st = (bf16_t*)smA;
    #pragma unroll
    for (int fn = 0; fn < 4; ++fn) {
        const int lcol = wc * 64 + fn * 16 + llo;
        const int col = n0 + lcol;
        const float b = (col < CV) ? bias[col] : 0.f;
        #pragma unroll
        for (int fm = 0; fm < 4; ++fm)
            #pragma unroll
            for (int r = 0; r < 4; ++r)
                st[(wr * 64 + fm * 16 + lhi * 4 + r) * 128 + lcol]
                    = (bf16_t)(acc[fm][fn][r] + b);
    }
    __syncthreads();
    #pragma unroll
    for (int i = 0; i < 8; ++i) {
        const int q = tid + i * 256;
        const int row = q >> 4, ch = q & 15;
        *(uint4*)(Cout + (size_t)(m0 + row) * CVP2 + n0 + ch * 8)
            = *(const uint4*)&st[row * 128 + ch * 8];
    }
}

// =======================================================================
// gate_split: split-K gate GEMM partials (bf16). (frozen from R18)
// =======================================================================
template<int TAG>
__global__ __launch_bounds__(256)
void gate_split(const bf16_t* __restrict__ A, int lda,
                const bf16_t* __restrict__ W, int ldw, int ktz,
                bf16_t* __restrict__ gpart)
{
    const int tid = threadIdx.x;
    const int w = tid >> 6, lane = tid & 63;
    const int llo = lane & 15, lhi = lane >> 4;
    const int n0 = blockIdx.x * 16;
    const int z  = blockIdx.y;
    const int kb = z * ktz;

    __shared__ __align__(16) uint8_t smA[2][16384];   // 128 rows x 128B
    __shared__ __align__(16) uint8_t smB[2][2048];    // 16 rows x 128B

    f32x4 acc0 = {0.f,0.f,0.f,0.f}, acc1 = {0.f,0.f,0.f,0.f};

    const int arow = tid >> 3, ac = tid & 7;
    const int asc = ac ^ (arow & 7);
    const int wvoff = (tid >> 6) * 1024;

    auto stage = [&](int buf, int ti) {
        const int k0 = (kb + ti) << 6;
        #pragma unroll
        for (int i = 0; i < 4; ++i) {
            const bf16_t* gp = A + (size_t)(arow + i * 32) * lda + k0 + asc * 8;
            __builtin_amdgcn_global_load_lds((glb_u32*)gp,
                (lds_u32*)(smA[buf] + i * 4096 + wvoff), 16, 0, 0);
        }
        if (tid < 128) {
            const int brow = tid >> 3, bc = tid & 7;
            const int bsc = bc ^ (brow & 7);
            const bf16_t* gp = W + (size_t)(n0 + brow) * ldw + k0 + bsc * 8;
            __builtin_amdgcn_global_load_lds((glb_u32*)gp,
                (lds_u32*)(smB[buf] + wvoff), 16, 0, 0);
        }
    };
    auto compute = [&](int buf) {
        const int r7 = llo & 7;
        #pragma unroll
        for (int kk = 0; kk < 2; ++kk) {
            const int coff = ((kk * 4 + lhi) ^ r7) << 4;
            bf16x8 a0 = *(const bf16x8*)(smA[buf] + (w * 32 + llo) * 128 + coff);
            bf16x8 a1 = *(const bf16x8*)(smA[buf] + (w * 32 + 16 + llo) * 128 + coff);
            bf16x8 bb = *(const bf16x8*)(smB[buf] + llo * 128 + coff);
            acc0 = __builtin_amdgcn_mfma_f32_16x16x32_bf16(a0, bb, acc0, 0, 0, 0);
            acc1 = __builtin_amdgcn_mfma_f32_16x16x32_bf16(a1, bb, acc1, 0, 0, 0);
        }
    };

    stage(0, 0);
    __syncthreads();
    int cur = 0;
    for (int ti = 0; ti < ktz; ++ti) {
        if (ti + 1 < ktz) stage(cur ^ 1, ti + 1);
        compute(cur);
        __syncthreads();
        cur ^= 1;
    }

    bf16_t* gp = gpart + (size_t)z * CB * G4;
    const int col = n0 + llo;
    #pragma unroll
    for (int r = 0; r < 4; ++r) {
        gp[(size_t)(w * 32 + lhi * 4 + r) * G4 + col] = (bf16_t)acc0[r];
        gp[(size_t)(w * 32 + 16 + lhi * 4 + r) * G4 + col] = (bf16_t)acc1[r];
    }
}

// =======================================================================
// lstm_attn: 1024 threads. (frozen from R18)
// =======================================================================
__global__ __launch_bounds__(1024)
void lstm_attn(const bf16_t* __restrict__ gpart, const bf16_t* __restrict__ gpre_fc,
               const bf16_t* __restrict__ gemb,
               const float* __restrict__ cbias, float* __restrict__ c_att,
               const bf16_t* __restrict__ p_att, const bf16_t* __restrict__ att_e,
               const bf16_t* __restrict__ h2att_wT, const float* __restrict__ h2att_b,
               const float* __restrict__ alpha_w, const float* __restrict__ alpha_b,
               bf16_t* __restrict__ xh_nxt, bf16_t* __restrict__ xl_cur)
{
    __shared__ float sh[CH];
    __shared__ float shq[CAH];
    __shared__ float se[64], salpha[64];
    const int b = blockIdx.x, tid = threadIdx.x;   // 0..1023

    {
        const int j = tid;
        float g0 = 0.f, g1 = 0.f, g2 = 0.f, g3 = 0.f;
        #pragma unroll
        for (int z = 0; z < 4; ++z) {
            bf16x4 g = *(const bf16x4*)(gpart + (size_t)z * CB * G4 + (size_t)b * G4 + 4 * j);
            g0 += (float)g[0]; g1 += (float)g[1]; g2 += (float)g[2]; g3 += (float)g[3];
        }
        f32x4 cb = *(const f32x4*)(cbias + 4 * j);
        bf16x4 gf4 = *(const bf16x4*)(gpre_fc + (size_t)b * G4 + 4 * j);
        bf16x4 ge4 = *(const bf16x4*)(gemb + (size_t)b * G4 + 4 * j);
        const float gi = g0 + cb[0] + (float)gf4[0] + (float)ge4[0];
        const float gf = g1 + cb[1] + (float)gf4[1] + (float)ge4[1];
        const float gg = g2 + cb[2] + (float)gf4[2] + (float)ge4[2];
        const float go = g3 + cb[3] + (float)gf4[3] + (float)ge4[3];
        const float si = 1.f / (1.f + expf(-gi));
        const float sf = 1.f / (1.f + expf(-gf));
        const float so = 1.f / (1.f + expf(-go));
        const float cn = sf * c_att[b * CH + j] + si * tanhf(gg);
        const float hn = so * tanhf(cn);
        c_att[b * CH + j] = cn;
        sh[j] = hn;
        const bf16_t hb = (bf16_t)hn;
        xh_nxt[(size_t)b * XH + 1024 + j] = hb;
        xl_cur[(size_t)b * XL3 + 1024 + j] = hb;
    }
    __syncthreads();

    {
        const int q2 = tid & 1, n = tid >> 1;
        const bf16_t* wrow = h2att_wT + (size_t)n * CH + q2 * 512;
        float s = 0.f;
        #pragma unroll 4
        for (int k = 0; k < 512; k += 8) {
            bf16x8 w8 = *(const bf16x8*)(wrow + k);
            #pragma unroll
            for (int j = 0; j < 8; ++j) s = fmaf((float)w8[j], sh[q2 * 512 + k + j], s);
        }
        s += __shfl_xor(s, 1);
        if (q2 == 0) shq[n] = s + h2att_b[n];
    }
    __syncthreads();

    {
        const int wave = tid >> 6, lane = tid & 63;
        for (int n = wave; n < CNREG; n += 16) {
            const bf16_t* pr = p_att + ((size_t)b * CNREG + n) * CAH;
            float s = 0.f;
            #pragma unroll
            for (int q = 0; q < CAH / 64; ++q) {
                const int d = lane + q * 64;
                s += alpha_w[d] * tanhf((float)pr[d] + shq[d]);
            }
            for (int off = 32; off; off >>= 1) s += __shfl_down(s, off);
            if (lane == 0) se[n] = s + alpha_b[0];
        }
    }
    __syncthreads();

    {
        float mx = -1e30f;
        for (int n = 0; n < CNREG; ++n) mx = fmaxf(mx, se[n]);
        float sum = 0.f;
        for (int n = 0; n < CNREG; ++n) sum += expf(se[n] - mx);
        if (tid < CNREG) salpha[tid] = expf(se[tid] - mx) / sum;
    }
    __syncthreads();

    {
        const int d = tid;
        float s = 0.f;
        const bf16_t* ae = att_e + (size_t)b * CNREG * CFE + d;
        #pragma unroll 4
        for (int n = 0; n < CNREG; ++n)
            s = fmaf(salpha[n], (float)ae[(size_t)n * CFE], s);
        xl_cur[(size_t)b * XL3 + d] = (bf16_t)s;
    }
}

// ---- lstm_flat (frozen from R18) ----
__global__ __launch_bounds__(256)
void lstm_flat(const bf16_t* __restrict__ gpart, const float* __restrict__ cbias,
               float* __restrict__ c,
               bf16_t* __restrict__ xh_nxt, bf16_t* __restrict__ xl_nxt,
               bf16_t* __restrict__ h_all, int t)
{
    const int idx = blockIdx.x * 256 + threadIdx.x;
    const int b = idx >> 10, j = idx & 1023;
    float g0 = 0.f, g1 = 0.f, g2 = 0.f, g3 = 0.f;
    #pragma unroll
    for (int z = 0; z < 4; ++z) {
        bf16x4 g = *(const bf16x4*)(gpart + (size_t)z * CB * G4 + (size_t)b * G4 + 4 * j);
        g0 += (float)g[0]; g1 += (float)g[1]; g2 += (float)g[2]; g3 += (float)g[3];
    }
    f32x4 cb = *(const f32x4*)(cbias + 4 * j);
    const float si = 1.f / (1.f + expf(-(g0 + cb[0])));
    const float sf = 1.f / (1.f + expf(-(g1 + cb[1])));
    const float so = 1.f / (1.f + expf(-(g3 + cb[3])));
    const float cn = sf * c[idx] + si * tanhf(g2 + cb[2]);
    const float hn = so * tanhf(cn);
    c[idx] = cn;
    const bf16_t hb = (bf16_t)hn;
    xh_nxt[(size_t)b * XH + j] = hb;
    xl_nxt[(size_t)b * XL3 + 2048 + j] = hb;
    h_all[((size_t)b * (CT - 1) + t) * CH + j] = hb;
}

// ---------------- prep kernels (frozen) ----------------
__global__ void convert_pad(const float* __restrict__ src, bf16_t* __restrict__ dst,
                            int C, int Cp)
{
    const int r = blockIdx.y;
    const int c = blockIdx.x * 256 + threadIdx.x;
    if (c >= Cp) return;
    dst[(size_t)r * Cp + c] = (c < C) ? (bf16_t)src[(size_t)r * C + c] : (bf16_t)0.f;
}

__global__ void convert_perm(const float* __restrict__ src, int srcld, int scol0,
                             int valid, bf16_t* __restrict__ dst, int dstld, int dcol0,
                             int ncols)
{
    const int rp = blockIdx.y;
    const int c = blockIdx.x * 256 + threadIdx.x;
    if (c >= ncols) return;
    const int rs = (rp & 3) * 1024 + (rp >> 2);
    const float v = (c < valid) ? src[(size_t)rs * srcld + scol0 + c] : 0.f;
    dst[(size_t)rp * dstld + dcol0 + c] = (bf16_t)v;
}

__global__ void bias_perm(const float* __restrict__ bih, const float* __restrict__ bhh,
                          float* __restrict__ dst)
{
    const int rp = blockIdx.x * 256 + threadIdx.x;
    if (rp >= G4) return;
    const int rs = (rp & 3) * 1024 + (rp >> 2);
    dst[rp] = bih[rs] + bhh[rs];
}

__global__ __launch_bounds__(256)
void transpose_convert(const float* __restrict__ src, bf16_t* __restrict__ dst,
                       int K, int N)
{
    __shared__ float tile[32][33];
    const int n0 = blockIdx.x * 32, k0 = blockIdx.y * 32;
    const int tx = threadIdx.x & 31, ty = threadIdx.x >> 5;
    #pragma unroll
    for (int i = 0; i < 4; ++i) {
        const int k = k0 + ty + i * 8, n = n0 + tx;
        tile[ty + i * 8][tx] = (k < K && n < N) ? src[(size_t)k * N + n] : 0.f;
    }
    __syncthreads();
    #pragma unroll
    for (int i = 0; i < 4; ++i) {
        const int n = n0 + ty + i * 8, k = k0 + tx;
        if (n < N && k < K) dst[(size_t)n * K + k] = (bf16_t)tile[tx][ty + i * 8];
    }
}

__global__ void emb_all(const float* __restrict__ emb_w,
                        const int* __restrict__ captions, bf16_t* __restrict__ w_emb)
{
    const int r = blockIdx.y;
    const int j = blockIdx.x * 256 + threadIdx.x;
    const int t = r >> 7, b = r & 127;
    const int tok = captions[b * CT + t];
    const float v = (j < CWE) ? fmaxf(emb_w[(size_t)tok * CWE + j], 0.f) : 0.f;
    w_emb[(size_t)r * 1024 + j] = (bf16_t)v;
}

// ---- log-softmax from bf16 logits [2048][CVP2] -> fp32 out [2048][CV] ----
__global__ __launch_bounds__(256)
void logsoftmax_bf(const bf16_t* __restrict__ lg, float* __restrict__ out)
{
    __shared__ float red[4];
    const int r = blockIdx.x, tid = threadIdx.x;
    const bf16_t* row = lg + (size_t)r * CVP2;

    float v[48];
    float mx = -1e30f;
    #pragma unroll
    for (int i = 0; i < 6; ++i) {
        const int c = tid + i * 256;
        if (c < 1500) {
            bf16x8 x = *(const bf16x8*)(row + c * 8);
            #pragma unroll
            for (int j = 0; j < 8; ++j) {
                v[i * 8 + j] = (float)x[j];
                mx = fmaxf(mx, v[i * 8 + j]);
            }
        } else {
            #pragma unroll
            for (int j = 0; j < 8; ++j) v[i * 8 + j] = -1e30f;
        }
    }
    for (int off = 32; off; off >>= 1) mx = fmaxf(mx, __shfl_down(mx, off));
    if ((tid & 63) == 0) red[tid >> 6] = mx;
    __syncthreads();
    mx = fmaxf(fmaxf(red[0], red[1]), fmaxf(red[2], red[3]));
    __syncthreads();

    float sum = 0.f;
    #pragma unroll
    for (int i = 0; i < 6; ++i)
        if (tid + i * 256 < 1500)
            #pragma unroll
            for (int j = 0; j < 8; ++j) sum += expf(v[i * 8 + j] - mx);
    for (int off = 32; off; off >>= 1) sum += __shfl_down(sum, off);
    if ((tid & 63) == 0) red[tid >> 6] = sum;
    __syncthreads();
    sum = red[0] + red[1] + red[2] + red[3];
    const float lse = mx + logf(sum);

    #pragma unroll
    for (int i = 0; i < 6; ++i) {
        const int c = tid + i * 256;
        if (c < 1500) {
            float* o = out + (size_t)r * CV + c * 8;
            float4 a = make_float4(v[i*8+0]-lse, v[i*8+1]-lse, v[i*8+2]-lse, v[i*8+3]-lse);
            float4 bq = make_float4(v[i*8+4]-lse, v[i*8+5]-lse, v[i*8+6]-lse, v[i*8+7]-lse);
            *(float4*)o = a;
            *(float4*)(o + 4) = bq;
        }
    }
}

// ---------------- launch ----------------
extern "C" void kernel_launch(void* const* d_in, const int* in_sizes, int n_in,
                              void* d_out, int out_size, void* d_ws, size_t ws_size,
                              hipStream_t stream)
{
    const float* fc_feats  = (const float*)d_in[0];
    const float* att_feats = (const float*)d_in[1];
    const int*   captions  = (const int*)  d_in[2];
    const float* emb_w     = (const float*)d_in[3];
    const float* fc_w      = (const float*)d_in[4];
    const float* fc_b      = (const float*)d_in[5];
    const float* atte_w    = (const float*)d_in[6];
    const float* atte_b    = (const float*)d_in[7];
    const float* ctx_w     = (const float*)d_in[8];
    const float* ctx_b     = (const float*)d_in[9];
    const float* attl_wih  = (const float*)d_in[10];
    const float* attl_whh  = (const float*)d_in[11];
    const float* attl_bih  = (const float*)d_in[12];
    const float* attl_bhh  = (const float*)d_in[13];
    const float* h2att_w   = (const float*)d_in[14];
    const float* h2att_b   = (const float*)d_in[15];
    const float* alpha_w   = (const float*)d_in[16];
    const float* alpha_b   = (const float*)d_in[17];
    const float* langl_wih = (const float*)d_in[18];
    const float* langl_whh = (const float*)d_in[19];
    const float* langl_bih = (const float*)d_in[20];
    const float* langl_bhh = (const float*)d_in[21];
    const float* cls_w     = (const float*)d_in[22];
    const float* cls_b     = (const float*)d_in[23];

    float* out = (float*)d_out;

    // ---- workspace layout ----
    char* p = (char*)d_ws;
    auto alloc_bf = [&](size_t e) { bf16_t* q = (bf16_t*)p; p += e * 2; return q; };
    auto alloc_f  = [&](size_t e) { float*  q = (float*) p; p += e * 4; return q; };

    bf16_t* Wcat_att    = alloc_bf((size_t)G4 * XH);
    bf16_t* Wcat_lang   = alloc_bf((size_t)G4 * XL3);
    bf16_t* Win_fc      = alloc_bf((size_t)G4 * 1024);
    bf16_t* Win_emb     = alloc_bf((size_t)G4 * 1024);
    bf16_t* fc_wT_b     = alloc_bf((size_t)CFE * CFEAT);
    bf16_t* atte_wT_b   = alloc_bf((size_t)CFE * CFEAT);
    bf16_t* ctx_wT_b    = alloc_bf((size_t)CAH * CFE);
    bf16_t* h2att_wT_b  = alloc_bf((size_t)CAH * CH);
    bf16_t* cls_wT_b    = alloc_bf((size_t)CVP2 * CH);
    bf16_t* fc_feats_b  = alloc_bf((size_t)CB * CFEAT);
    bf16_t* att_feats_b = alloc_bf((size_t)CB * CNREG * CFEAT);  // Gemb aliases this
    bf16_t* att_e_b     = alloc_bf((size_t)CB * CNREG * CFE);
    bf16_t* w_emb       = alloc_bf((size_t)(CT - 1) * CB * 1024);
    bf16_t* fc_e_b      = alloc_bf((size_t)CB * CFE);
    bf16_t* gpre_fc     = alloc_bf((size_t)CB * G4);
    bf16_t* xh0         = alloc_bf((size_t)CB * XH);
    bf16_t* xh1         = alloc_bf((size_t)CB * XH);
    bf16_t* xl3a        = alloc_bf((size_t)CB * XL3);
    bf16_t* xl3b        = alloc_bf((size_t)CB * XL3);
    bf16_t* h_all       = alloc_bf((size_t)CB * (CT - 1) * CH);
    bf16_t* p_att       = alloc_bf((size_t)CB * CNREG * CAH);
    bf16_t* gpart       = alloc_bf((size_t)4 * CB * G4);
    float*  cbias_att   = alloc_f (G4);
    float*  cbias_lang  = alloc_f (G4);
    float*  c_att       = alloc_f ((size_t)CB * CH);
    float*  c_lang      = alloc_f ((size_t)CB * CH);

    bf16_t* Gemb   = att_feats_b;         // dead after att_e GEMM
    bf16_t* logits = Wcat_att;            // dead after recurrence loop (exact fit)

    // ---- zero state ----
    hipMemsetAsync(xh0,    0, (size_t)CB * XH * 2, stream);
    hipMemsetAsync(xh1,    0, (size_t)CB * XH * 2, stream);
    hipMemsetAsync(xl3a,   0, (size_t)CB * XL3 * 2, stream);
    hipMemsetAsync(xl3b,   0, (size_t)CB * XL3 * 2, stream);
    hipMemsetAsync(c_att,  0, (size_t)CB * CH * 4, stream);
    hipMemsetAsync(c_lang, 0, (size_t)CB * CH * 4, stream);
    hipMemsetAsync(cls_wT_b + (size_t)CV * CH, 0, (size_t)(CVP2 - CV) * CH * 2, stream);

    const dim3 blk(256);
    auto mk = [](const bf16_t* A, int lda, const bf16_t* W, int ldw, int kt) {
        return Seg{A, W, lda, ldw, kt};
    };

    // ---- one-time weight prep ----
    convert_perm<<<dim3(4, G4), blk, 0, stream>>>(attl_wih, 3048, 0, 1024, Wcat_att, XH, 0, 1024);
    convert_perm<<<dim3(4, G4), blk, 0, stream>>>(attl_whh, 1024, 0, 1024, Wcat_att, XH, 1024, 1024);
    convert_perm<<<dim3(4, G4), blk, 0, stream>>>(attl_wih, 3048, 1024, 1024, Win_fc, 1024, 0, 1024);
    convert_perm<<<dim3(4, G4), blk, 0, stream>>>(attl_wih, 3048, 2048, 1000, Win_emb, 1024, 0, 1024);
    convert_perm<<<dim3(8, G4), blk, 0, stream>>>(langl_wih, 2048, 0, 2048, Wcat_lang, XL3, 0, 2048);
    convert_perm<<<dim3(4, G4), blk, 0, stream>>>(langl_whh, 1024, 0, 1024, Wcat_lang, XL3, 2048, 1024);
    bias_perm<<<16, blk, 0, stream>>>(attl_bih, attl_bhh, cbias_att);
    bias_perm<<<16, blk, 0, stream>>>(langl_bih, langl_bhh, cbias_lang);
    convert_pad<<<dim3(8, CB), blk, 0, stream>>>(fc_feats, fc_feats_b, CFEAT, CFEAT);
    convert_pad<<<dim3(8, CB * CNREG), blk, 0, stream>>>(att_feats, att_feats_b, CFEAT, CFEAT);
    transpose_convert<<<dim3(CFE/32, CFEAT/32), blk, 0, stream>>>(fc_w,    fc_wT_b,    CFEAT, CFE);
    transpose_convert<<<dim3(CFE/32, CFEAT/32), blk, 0, stream>>>(atte_w,  atte_wT_b,  CFEAT, CFE);
    transpose_convert<<<dim3(CAH/32, CFE/32),   blk, 0, stream>>>(ctx_w,   ctx_wT_b,   CFE,   CAH);
    transpose_convert<<<dim3(CAH/32, CH/32),    blk, 0, stream>>>(h2att_w, h2att_wT_b, CH,    CAH);
    transpose_convert<<<dim3(CDIV(CV,32), CH/32), blk, 0, stream>>>(cls_w, cls_wT_b,   CH,    CV);
    emb_all<<<dim3(4, (CT - 1) * CB), blk, 0, stream>>>(emb_w, captions, w_emb);

    // ---- preamble GEMMs (kt in BK=32 units) ----
    pre_gemm<true,true,2><<<16, blk, 0, stream>>>(
        mk(fc_feats_b, CFEAT, fc_wT_b, CFEAT, 64), 16, fc_b, fc_e_b, CFE);
    pre_gemm<true,true,2><<<576, blk, 0, stream>>>(
        mk(att_feats_b, CFEAT, atte_wT_b, CFEAT, 64), 16, atte_b, att_e_b, CFE);
    pre_gemm<false,true,2><<<288, blk, 0, stream>>>(
        mk(att_e_b, CFE, ctx_wT_b, CFE, 32), 8, ctx_b, p_att, CAH);
    pre_gemm<false,true,1><<<64, blk, 0, stream>>>(
        mk(fc_e_b, CFE, Win_fc, 1024, 32), 1, nullptr, gpre_fc, G4);
    pre_gemm<false,true,3><<<1024, blk, 0, stream>>>(
        mk(w_emb, 1024, Win_emb, 1024, 32), 0, nullptr, Gemb, G4);

    // ---- recurrence: 4 launches per step ----
    for (int t = 0; t < CT - 1; ++t) {
        bf16_t* xh_cur = (t & 1) ? xh1 : xh0;
        bf16_t* xh_nxt = (t & 1) ? xh0 : xh1;
        bf16_t* xl_cur = (t & 1) ? xl3b : xl3a;
        bf16_t* xl_nxt = (t & 1) ? xl3a : xl3b;

        gate_split<0><<<dim3(256, 4), blk, 0, stream>>>(
            xh_cur, XH, Wcat_att, XH, 8, gpart);

        lstm_attn<<<CB, dim3(1024), 0, stream>>>(
            gpart, gpre_fc, Gemb + (size_t)t * CB * G4, cbias_att, c_att,
            p_att, att_e_b, h2att_wT_b, h2att_b, alpha_w, alpha_b,
            xh_nxt, xl_cur);

        gate_split<1><<<dim3(256, 4), blk, 0, stream>>>(
            xl_cur, XL3, Wcat_lang, XL3, 12, gpart);

        lstm_flat<<<512, blk, 0, stream>>>(
            gpart, cbias_lang, c_lang, xh_nxt, xl_nxt, h_all, t);
    }

    // ---- deferred classifier + log-softmax ----
    cls_gemm<<<1536, blk, 0, stream>>>(h_all, cls_wT_b, cls_b, logits);
    logsoftmax_bf<<<2048, blk, 0, stream>>>(logits, out);
}